// Round 8
// baseline (308.383 us; speedup 1.0000x reference)
//
#include <hip/hip_runtime.h>

typedef unsigned short u16;
typedef unsigned int u32;
typedef float f32x4 __attribute__((ext_vector_type(4)));
typedef __bf16 bf16x8 __attribute__((ext_vector_type(8)));
typedef u32 u32x4 __attribute__((ext_vector_type(4)));

#define T_TOK 4096
#define HDIM 1024
#define IDIM 512
#define NEXP 32
#define KSEL 8
#define CAPE 2048
#define NROW (NEXP*CAPE + T_TOK)   // 69632 rows total (experts + shared)
#define MAXTILE 528                // 33 experts * 16 y-tiles max
#define MAXWG  (MAXTILE*4)         // 2112
#define CVTWG  512                 // guaranteed converter blocks appended to GEMM1

__device__ __forceinline__ u16 f32_to_bf16(float f) {
  u32 x = __float_as_uint(f);
  u32 r = (x + 0x7FFFu + ((x >> 16) & 1u)) >> 16;   // RNE; inputs finite
  return (u16)r;
}
__device__ __forceinline__ float bf16_to_f32(u16 u) {
  return __uint_as_float(((u32)u) << 16);
}

// ---------------- k_pre: gate only (fp64 logits + group top-k; fused x->bf16) ----------------
__global__ __launch_bounds__(256) void k_pre(const float* __restrict__ x, const float* __restrict__ gw,
                                             int* __restrict__ idx, float* __restrict__ wts,
                                             u16* __restrict__ xb, int* __restrict__ done) {
  __shared__ float xs[32][129];
  __shared__ float gs_[32][129];
  __shared__ double sc[32][32];
  const int tid = threadIdx.x;
  const int t0 = blockIdx.x * 32;
  const int tl = tid & 31, g = tid >> 5;
  if (blockIdx.x == 0 && tid == 0) done[0] = 0;   // reset assign rendezvous (runs before k_assign)
  double acc0 = 0, acc1 = 0, acc2 = 0, acc3 = 0;
  for (int k0 = 0; k0 < HDIM; k0 += 128) {
#pragma unroll
    for (int q = 0; q < 4; ++q) {
      int f = tid + 256 * q;
      int row = f >> 5, c4 = (f & 31) * 4;
      float4 v = *reinterpret_cast<const float4*>(x + (long)(t0 + row) * HDIM + k0 + c4);
      xs[row][c4+0]=v.x; xs[row][c4+1]=v.y; xs[row][c4+2]=v.z; xs[row][c4+3]=v.w;
      ushort4 xv; xv.x=f32_to_bf16(v.x); xv.y=f32_to_bf16(v.y); xv.z=f32_to_bf16(v.z); xv.w=f32_to_bf16(v.w);
      *reinterpret_cast<ushort4*>(xb + (long)(t0 + row) * HDIM + k0 + c4) = xv;   // fused x convert
      float4 w = *reinterpret_cast<const float4*>(gw + (long)row * HDIM + k0 + c4);
      gs_[row][c4+0]=w.x; gs_[row][c4+1]=w.y; gs_[row][c4+2]=w.z; gs_[row][c4+3]=w.w;
    }
    __syncthreads();
#pragma unroll 4
    for (int kk = 0; kk < 128; ++kk) {
      double xv = (double)xs[tl][kk];
      acc0 += xv * (double)gs_[g     ][kk];
      acc1 += xv * (double)gs_[g +  8][kk];
      acc2 += xv * (double)gs_[g + 16][kk];
      acc3 += xv * (double)gs_[g + 24][kk];
    }
    __syncthreads();
  }
  sc[tl][g     ] = acc0;   // raw logits; sigmoid monotonic -> same top-k order
  sc[tl][g +  8] = acc1;
  sc[tl][g + 16] = acc2;
  sc[tl][g + 24] = acc3;
  __syncthreads();
  if (tid < 32) {
    int t = t0 + tid;
    double gsc[8];
#pragma unroll
    for (int gg = 0; gg < 8; ++gg) {
      double mx = sc[tid][4*gg];
#pragma unroll
      for (int j = 1; j < 4; ++j) mx = fmax(mx, sc[tid][4*gg + j]);
      gsc[gg] = mx;
    }
    unsigned gmask = 0;
    for (int it = 0; it < 4; ++it) {          // top-4 groups, strict >, first index wins
      double best = -1e300; int bi = 0;
      for (int gg = 0; gg < 8; ++gg)
        if (!((gmask >> gg) & 1) && gsc[gg] > best) { best = gsc[gg]; bi = gg; }
      gmask |= 1u << bi;
    }
    unsigned emask = 0; int ei[KSEL]; double ew[KSEL]; double wsum = 0;
    for (int it = 0; it < KSEL; ++it) {       // top-8 experts on logits
      double best = -1e300; int bi = 0;
      for (int e = 0; e < NEXP; ++e)
        if (((gmask >> (e >> 2)) & 1) && !((emask >> e) & 1)) {
          double v = sc[tid][e];
          if (v > best) { best = v; bi = e; }
        }
      emask |= 1u << bi; ei[it] = bi;
      double sg = 1.0 / (1.0 + exp(-best));   // sigmoid only for selected
      ew[it] = sg; wsum += sg;
    }
    double s = 2.5 / (wsum + 1e-20);
    for (int k = 0; k < KSEL; ++k) { idx[t*KSEL + k] = ei[k]; wts[t*KSEL + k] = (float)(ew[k] * s); }
  }
}

// ---------------- capacity assignment (ballot-scan) + inline tile scheduler (r5 verbatim) ----------------
__global__ __launch_bounds__(1024) void k_assign(const int* __restrict__ idx,
                                                 int* __restrict__ etok, int* __restrict__ pos,
                                                 int* __restrict__ cnts,
                                                 int* __restrict__ list, int* __restrict__ tot,
                                                 int* __restrict__ done) {
  const int e = blockIdx.x;
  const int tid = threadIdx.x;
  int base = 0;
  if (e == NEXP) {
    for (int t = tid; t < T_TOK; t += 1024) etok[NEXP*CAPE + t] = t;
    base = T_TOK;
  } else {
    __shared__ int wbase[17];
    const int wid = tid >> 6, lane = tid & 63;
    for (int c = 0; c < T_TOK / 1024; ++c) {
      int t = c * 1024 + tid;
      int found = -1;
#pragma unroll
      for (int k = 0; k < KSEL; ++k) if (idx[t*KSEL + k] == e) found = k;
      unsigned long long mask = __ballot(found >= 0);
      int myrank = __popcll(mask & ((1ull << lane) - 1ull));
      __syncthreads();
      if (lane == 0) wbase[wid] = __popcll(mask);
      __syncthreads();
      if (tid == 0) {
        int run = 0;
#pragma unroll
        for (int w = 0; w < 16; ++w) { int v = wbase[w]; wbase[w] = run; run += v; }
        wbase[16] = run;
      }
      __syncthreads();
      if (found >= 0) {
        int slot = base + wbase[wid] + myrank;
        pos[t*KSEL + found] = slot;
        if (slot < CAPE) etok[e*CAPE + slot] = t;
      }
      base += wbase[16];
      __syncthreads();
    }
    base = min(base, CAPE);
  }
  if (tid == 0) {
    cnts[e] = base;
    __threadfence();
    if (atomicAdd(done, 1) == NEXP) {          // last finisher builds the compact work list
      __threadfence();
      int run = 0;
      for (int ee = 0; ee <= NEXP; ++ee) {
        int c = atomicAdd(&cnts[ee], 0);       // device-scope read
        int nt = (c + 255) >> 8;
        for (int i = 0; i < nt; ++i) list[run + i] = ee * 16 + i;
        run += nt;
      }
      tot[0] = run * 4;
    }
  }
}

#define GLDS(gp, lp) __builtin_amdgcn_global_load_lds( \
    (const __attribute__((address_space(1))) void*)(gp), \
    (__attribute__((address_space(3))) void*)(lp), 16, 0, 0)
#define SB __builtin_amdgcn_sched_barrier(0)

// ---------------- GEMM1: 256x256, BK=64, 8-phase; A bf16 via global_load_lds; B fp32 direct ----------------
// B path: fp32 -> regs with 2-tile lookahead; {vmcnt-wait; cvt_pk; swizzled ds_write; reload} placed
// AFTER the q1/q3 MFMA clusters so the ds_writes drain in the next phase's shadow (fixes r4's
// lgkmcnt(0)-drains-fresh-writes defect). FIFO per tile: q0 A1(t+1)[2], q1 B0(t+2)[4],
// q2 A0(t+2)[2], q3 B1(t+2)[4]. Waits: q1-end vmcnt(8) drains B0(t+1) regs; q3-end vmcnt(6)
// drains B1(t+1) regs + both A(t+1) halves (the K-tile boundary). Inactive blocks convert w2->bf16.
__global__ __launch_bounds__(512, 2) void k_gemm1f(const u16* __restrict__ A,
                                                   const float* __restrict__ Bf,
                                                   const float* __restrict__ Bs1, const float* __restrict__ Bs3,
                                                   u16* __restrict__ out,
                                                   const int* __restrict__ etok, const int* __restrict__ cnts,
                                                   const int* __restrict__ list, const int* __restrict__ tot,
                                                   const float* __restrict__ cvsrc, const float* __restrict__ cvsrc2,
                                                   u16* __restrict__ cvdst, long cvt_n8) {
  constexpr int KDIM = HDIM, NT = KDIM / 64, MSK = NT - 1;
  __shared__ u16 lds[65536];            // [dbuf 2][A 32KB | B 32KB]

  const int n = tot[0];
  const int bid0 = blockIdx.x;
  const int tid = threadIdx.x;
  if (bid0 >= n) {
    // converter service: w2 (+sw2) fp32 -> bf16 in GEMM1's shadow
    const long nb = (long)gridDim.x - n;
    const long stride = nb * 512;
    for (long j = (long)(bid0 - n) * 512 + tid; j < cvt_n8; j += stride) {
      int e   = (int)(j >> 16);
      int rem = (int)(j & 65535);
      const float* s = ((e < NEXP) ? cvsrc + ((size_t)e << 19) : cvsrc2) + (size_t)rem * 8;
      float4 a = reinterpret_cast<const float4*>(s)[0];
      float4 b = reinterpret_cast<const float4*>(s)[1];
      ushort4 lo, hi;
      lo.x=f32_to_bf16(a.x); lo.y=f32_to_bf16(a.y); lo.z=f32_to_bf16(a.z); lo.w=f32_to_bf16(a.w);
      hi.x=f32_to_bf16(b.x); hi.y=f32_to_bf16(b.y); hi.z=f32_to_bf16(b.z); hi.w=f32_to_bf16(b.w);
      u16* d = cvdst + ((size_t)e << 19) + (size_t)rem * 8;
      reinterpret_cast<ushort4*>(d)[0] = lo;
      reinterpret_cast<ushort4*>(d)[1] = hi;
    }
    return;
  }
  const int q = n >> 3, r = n & 7, xc = bid0 & 7, o = bid0 >> 3;
  const int wg = (xc < r ? xc * (q + 1) : r * (q + 1) + (xc - r) * q) + o;
  const int item = list[wg >> 2];
  const int e = item >> 4, yt = item & 15, xt = wg & 3;

  const int cnt = cnts[e];
  const int brow = yt * 256;
  const int rv = min(256, cnt - brow);
  const long rowbase = (long)e * CAPE;

  const int wave = tid >> 6, lane = tid & 63;
  const int wm = wave >> 2, wn = wave & 3;
  const int lr = lane & 15;
  const int lk = (lane >> 4) * 16;

  // A staging pointers (gathered rows, pre-swizzled source)
  const u16* pa[4];
#pragma unroll
  for (int j = 0; j < 4; ++j) {
    int row = j*64 + (tid >> 3);
    int sl = (tid & 7) ^ (row & 7);
    long arow = (row < rv) ? (long)etok[rowbase + brow + row] : 0L;
    pa[j] = A + arow * KDIM + sl * 8;
  }
  // B fp32 per-thread row pointers (w1/w3 16-row interleave map)
  const float* pbF[2];
#pragma unroll
  for (int h = 0; h < 2; ++h) {
    int rbw = xt*256 + h*128 + (tid >> 2);
    int sel = (rbw >> 4) & 1;
    int srow = ((rbw >> 5) << 4) | (rbw & 15);
    const float* bs;
    if (e < NEXP) bs = Bf + ((size_t)e * 1024 + sel * 512 + srow) * (size_t)KDIM;
    else          bs = (sel ? Bs3 : Bs1) + (size_t)srow * KDIM;
    pbF[h] = bs + (tid & 3) * 16;
  }

  auto STAGEA = [&](int st, int h) {
    int dbase = (st & 1) * 32768;
#pragma unroll
    for (int s = 0; s < 2; ++s) {
      int j = h*2 + s;
      GLDS(pa[j] + (st & MSK) * 64, &lds[dbase + j*4096 + wave*512]);
    }
  };
  auto LOADB = [&](float4* rr, int st, int h) {
    const float* p = pbF[h] + (size_t)min(st, NT - 1) * 64;
#pragma unroll
    for (int i = 0; i < 4; ++i) rr[i] = reinterpret_cast<const float4*>(p)[i];
  };
  auto CVTW = [&](const float4* rr, int slot, int h) {  // 16 f32 -> bf16 -> 2 swizzled ds_write_b128
    int rbt = h*128 + (tid >> 2);
    u32 w[8];
#pragma unroll
    for (int i = 0; i < 8; ++i) {
      float f0 = reinterpret_cast<const float*>(rr)[2*i];
      float f1 = reinterpret_cast<const float*>(rr)[2*i + 1];
      asm("v_cvt_pk_bf16_f32 %0, %1, %2" : "=v"(w[i]) : "v"(f0), "v"(f1));
    }
    char* bp = (char*)lds + slot*65536 + 32768 + rbt*128;
    int c0 = ((tid & 3) * 2)     ^ (rbt & 7);
    int c1 = ((tid & 3) * 2 + 1) ^ (rbt & 7);
    *reinterpret_cast<u32x4*>(bp + c0*16) = (u32x4){w[0], w[1], w[2], w[3]};
    *reinterpret_cast<u32x4*>(bp + c1*16) = (u32x4){w[4], w[5], w[6], w[7]};
  };
  const char* ldsb = (const char*)lds;
  auto RD = [&](int d, int op, int rr, int kk) -> bf16x8 {
    int bc = (kk*64 + lk) ^ ((rr & 7) << 4);
    return *(const bf16x8*)(ldsb + (size_t)(d*65536 + op*32768 + rr*128 + bc));
  };

  f32x4 acc[8][4];
#pragma unroll
  for (int m = 0; m < 8; ++m)
#pragma unroll
    for (int nn = 0; nn < 4; ++nn) acc[m][nn] = (f32x4){0.f,0.f,0.f,0.f};

  float4 rB0[4], rB1[4];

  // ---- prologue (FIFO counts hand-tracked; see header comment) ----
  asm volatile("s_waitcnt vmcnt(0)" ::: "memory");   // drain etok/setup loads
  SB;
  LOADB(rB0, 0, 0);            // +4
  LOADB(rB1, 0, 1);            // +4
  STAGEA(0, 0); STAGEA(0, 1);  // +4  (out 12)
  asm volatile("s_waitcnt vmcnt(8)" ::: "memory"); SB;   // drains B0(0) regs
  CVTW(rB0, 0, 0);
  LOADB(rB0, 1, 0);            // out 12: [B1(0)4, A(0)4, B0(1)4]
  asm volatile("s_waitcnt vmcnt(8)" ::: "memory"); SB;   // drains B1(0) regs
  CVTW(rB1, 0, 1);
  LOADB(rB1, 1, 1);            // out 12: [A(0)4, B0(1)4, B1(1)4]
  STAGEA(1, 0);                // +2 A0(1) -> out 14
  asm volatile("s_waitcnt vmcnt(10)" ::: "memory"); SB;  // drains A(0) -> LDS tile0 A ready
  asm volatile("s_waitcnt lgkmcnt(0)" ::: "memory"); SB; // CVTW writes landed
  __builtin_amdgcn_s_barrier();

  bf16x8 a[4][2], b[2][2], b0h[2][2];

  for (int t = 0; t < NT; ++t) {
    const int d = t & 1;
    // ---------- q0: read A0(8)+B0(4); stage A1(t+1) ----------
#pragma unroll
    for (int m = 0; m < 4; ++m)
#pragma unroll
      for (int kk = 0; kk < 2; ++kk) a[m][kk] = RD(d, 0, wm*64 + m*16 + lr, kk);
#pragma unroll
    for (int nn = 0; nn < 2; ++nn)
#pragma unroll
      for (int kk = 0; kk < 2; ++kk) { b[nn][kk] = RD(d, 1, wn*32 + nn*16 + lr, kk); b0h[nn][kk] = b[nn][kk]; }
    STAGEA(t + 1, 1);
    __builtin_amdgcn_s_barrier();
    asm volatile("s_waitcnt lgkmcnt(0)" ::: "memory");
    SB;
    __builtin_amdgcn_s_setprio(1);
#pragma unroll
    for (int m = 0; m < 4; ++m)
#pragma unroll
      for (int nn = 0; nn < 2; ++nn)
#pragma unroll
        for (int kk = 0; kk < 2; ++kk)
          acc[m][nn] = __builtin_amdgcn_mfma_f32_16x16x32_bf16(a[m][kk], b[nn][kk], acc[m][nn], 0, 0, 0);
    __builtin_amdgcn_s_setprio(0);
    SB;
    __builtin_amdgcn_s_barrier();
    // ---------- q1: read B1(4); MFMA; then cvt+write B0(t+1), reload B0(t+2) ----------
#pragma unroll
    for (int nn = 0; nn < 2; ++nn)
#pragma unroll
      for (int kk = 0; kk < 2; ++kk) b[nn][kk] = RD(d, 1, 128 + wn*32 + nn*16 + lr, kk);
    __builtin_amdgcn_s_barrier();
    asm volatile("s_waitcnt lgkmcnt(0)" ::: "memory");
    SB;
    __builtin_amdgcn_s_setprio(1);
#pragma unroll
    for (int m = 0; m < 4; ++m)
#pragma unroll
      for (int nn = 0; nn < 2; ++nn)
#pragma unroll
        for (int kk = 0; kk < 2; ++kk)
          acc[m][2+nn] = __builtin_amdgcn_mfma_f32_16x16x32_bf16(a[m][kk], b[nn][kk], acc[m][2+nn], 0, 0, 0);
    __builtin_amdgcn_s_setprio(0);
    SB;
    asm volatile("s_waitcnt vmcnt(8)" ::: "memory");   // B0(t+1) regs landed (issued q1 of t-1)
    SB;
    CVTW(rB0, d ^ 1, 0);
    LOADB(rB0, t + 2, 0);
    __builtin_amdgcn_s_barrier();
    // ---------- q2: read A1(8); stage A0(t+2) ----------
#pragma unroll
    for (int m = 0; m < 4; ++m)
#pragma unroll
      for (int kk = 0; kk < 2; ++kk) a[m][kk] = RD(d, 0, 128 + wm*64 + m*16 + lr, kk);
    STAGEA(t + 2, 0);
    __builtin_amdgcn_s_barrier();
    asm volatile("s_waitcnt lgkmcnt(0)" ::: "memory");
    SB;
    __builtin_amdgcn_s_setprio(1);
#pragma unroll
    for (int m = 0; m < 4; ++m)
#pragma unroll
      for (int nn = 0; nn < 2; ++nn)
#pragma unroll
        for (int kk = 0; kk < 2; ++kk)
          acc[4+m][2+nn] = __builtin_amdgcn_mfma_f32_16x16x32_bf16(a[m][kk], b[nn][kk], acc[4+m][2+nn], 0, 0, 0);
    __builtin_amdgcn_s_setprio(0);
    SB;
    __builtin_amdgcn_s_barrier();
    // ---------- q3: no ds_reads (A1 + held B0); MFMA; then cvt+write B1(t+1), reload B1(t+2) ----------
    __builtin_amdgcn_s_barrier();
    asm volatile("s_waitcnt lgkmcnt(0)" ::: "memory");
    SB;
    __builtin_amdgcn_s_setprio(1);
#pragma unroll
    for (int m = 0; m < 4; ++m)
#pragma unroll
      for (int nn = 0; nn < 2; ++nn)
#pragma unroll
        for (int kk = 0; kk < 2; ++kk)
          acc[4+m][nn] = __builtin_amdgcn_mfma_f32_16x16x32_bf16(a[m][kk], b0h[nn][kk], acc[4+m][nn], 0, 0, 0);
    __builtin_amdgcn_s_setprio(0);
    SB;
    asm volatile("s_waitcnt vmcnt(6)" ::: "memory");   // B1(t+1) regs + A(t+1) both halves landed
    SB;
    CVTW(rB1, d ^ 1, 1);
    LOADB(rB1, t + 2, 1);
    __builtin_amdgcn_s_barrier();
  }

  // epilogue: C/D map col=lane&15, row=(lane>>4)*4+reg; silu(h1)*h3 -> u bf16
  const int rl = (lane >> 4) << 2;
#pragma unroll
  for (int mq = 0; mq < 2; ++mq)
#pragma unroll
    for (int m = 0; m < 4; ++m) {
      int rbase = mq*128 + wm*64 + m*16 + rl;
#pragma unroll
      for (int nq = 0; nq < 2; ++nq) {
        f32x4 h1 = acc[mq*4+m][nq*2], h3 = acc[mq*4+m][nq*2+1];
        int ucol = xt*128 + nq*64 + wn*16 + lr;
#pragma unroll
        for (int j = 0; j < 4; ++j) {
          int lrow = rbase + j;
          if (lrow < rv) {
            float v1 = h1[j];
            float uu = v1 / (1.f + __expf(-v1)) * h3[j];
            out[(size_t)(rowbase + brow + lrow) * IDIM + ucol] = f32_to_bf16(uu);
          }
        }
      }
    }
}

// ---------------- GEMM2: r5-verbatim bf16 grouped GEMM (256x256, BK=64, 8-phase vmcnt(6)) ----------------
template<int KDIM, bool GATHER, bool ACT>
__global__ __launch_bounds__(512, 2) void k_gemm8(const u16* __restrict__ A, const u16* __restrict__ Ball,
                                                  u16* __restrict__ out,
                                                  const int* __restrict__ etok, const int* __restrict__ cnts,
                                                  const int* __restrict__ list, const int* __restrict__ tot) {
  constexpr int NT = KDIM / 64;
  constexpr int MSK = NT - 1;
  __shared__ u16 lds[65536];

  const int n = tot[0];
  const int bid0 = blockIdx.x;
  const int tid = threadIdx.x;
  if (bid0 >= n) return;
  const int q = n >> 3, r = n & 7, xc = bid0 & 7, o = bid0 >> 3;
  const int wg = (xc < r ? xc * (q + 1) : r * (q + 1) + (xc - r) * q) + o;
  const int item = list[wg >> 2];
  const int e = item >> 4, yt = item & 15, xt = wg & 3;

  const int cnt = cnts[e];
  const int brow = yt * 256;
  const int rv = min(256, cnt - brow);
  const long rowbase = (long)e * CAPE;
  const u16* Bexp = Ball + (size_t)e * (size_t)(1024 * KDIM);

  const int wave = tid >> 6, lane = tid & 63;
  const int wm = wave >> 2, wn = wave & 3;
  const int lr = lane & 15;
  const int lk = (lane >> 4) * 16;

  const u16* pa[4]; const u16* pb[4];
#pragma unroll
  for (int j = 0; j < 4; ++j) {
    int row = j*64 + (tid >> 3);
    int sl = (tid & 7) ^ (row & 7);
    long arow;
    if (GATHER) arow = (row < rv) ? (long)etok[rowbase + brow + row] : 0L;
    else        arow = rowbase + brow + row;
    pa[j] = A + arow * KDIM + sl * 8;
    pb[j] = Bexp + ((long)(xt*256 + row)) * KDIM + sl * 8;
  }

  auto STAGE = [&](int st, int op, int h) {
    int dbase = (st & 1) * 32768 + op * 16384;
    const u16* const* pp = op ? pb : pa;
#pragma unroll
    for (int s = 0; s < 2; ++s) {
      int j = h*2 + s;
      GLDS(pp[j] + st * 64, &lds[dbase + j*4096 + wave*512]);
    }
  };
  const char* ldsb = (const char*)lds;
  auto RD = [&](int d, int op, int rr, int kk) -> bf16x8 {
    int bc = (kk*64 + lk) ^ ((rr & 7) << 4);
    return *(const bf16x8*)(ldsb + (size_t)(d*65536 + op*32768 + rr*128 + bc));
  };

  f32x4 acc[8][4];
#pragma unroll
  for (int m = 0; m < 8; ++m)
#pragma unroll
    for (int nn = 0; nn < 4; ++nn) acc[m][nn] = (f32x4){0.f,0.f,0.f,0.f};

  STAGE(0,0,0); STAGE(0,1,0); STAGE(0,0,1); STAGE(0,1,1);
  STAGE(1,0,0); STAGE(1,1,0); STAGE(1,1,1);
  asm volatile("s_waitcnt vmcnt(6)" ::: "memory");
  __builtin_amdgcn_sched_barrier(0);
  __builtin_amdgcn_s_barrier();

  bf16x8 a[4][2], b[2][2], b0h[2][2];

  for (int t = 0; t < NT; ++t) {
    const int d = t & 1;
#pragma unroll
    for (int m = 0; m < 4; ++m)
#pragma unroll
      for (int kk = 0; kk < 2; ++kk) a[m][kk] = RD(d, 0, wm*64 + m*16 + lr, kk);
#pragma unroll
    for (int nn = 0; nn < 2; ++nn)
#pragma unroll
      for (int kk = 0; kk < 2; ++kk) { b[nn][kk] = RD(d, 1, wn*32 + nn*16 + lr, kk); b0h[nn][kk] = b[nn][kk]; }
    STAGE((t+1) & MSK, 0, 1);
    __builtin_amdgcn_s_barrier();
    asm volatile("s_waitcnt lgkmcnt(0)" ::: "memory");
    __builtin_amdgcn_sched_barrier(0);
    __builtin_amdgcn_s_setprio(1);
#pragma unroll
    for (int m = 0; m < 4; ++m)
#pragma unroll
      for (int nn = 0; nn < 2; ++nn)
#pragma unroll
        for (int kk = 0; kk < 2; ++kk)
          acc[m][nn] = __builtin_amdgcn_mfma_f32_16x16x32_bf16(a[m][kk], b[nn][kk], acc[m][nn], 0, 0, 0);
    __builtin_amdgcn_s_setprio(0);
    __builtin_amdgcn_sched_barrier(0);
    __builtin_amdgcn_s_barrier();
#pragma unroll
    for (int nn = 0; nn < 2; ++nn)
#pragma unroll
      for (int kk = 0; kk < 2; ++kk) b[nn][kk] = RD(d, 1, 128 + wn*32 + nn*16 + lr, kk);
    STAGE((t+2) & MSK, 1, 0);
    __builtin_amdgcn_s_barrier();
    asm volatile("s_waitcnt lgkmcnt(0)" ::: "memory");
    __builtin_amdgcn_sched_barrier(0);
    __builtin_amdgcn_s_setprio(1);
#pragma unroll
    for (int m = 0; m < 4; ++m)
#pragma unroll
      for (int nn = 0; nn < 2; ++nn)
#pragma unroll
        for (int kk = 0; kk < 2; ++kk)
          acc[m][2+nn] = __builtin_amdgcn_mfma_f32_16x16x32_bf16(a[m][kk], b[nn][kk], acc[m][2+nn], 0, 0, 0);
    __builtin_amdgcn_s_setprio(0);
    __builtin_amdgcn_sched_barrier(0);
    __builtin_amdgcn_s_barrier();
#pragma unroll
    for (int m = 0; m < 4; ++m)
#pragma unroll
      for (int kk = 0; kk < 2; ++kk) a[m][kk] = RD(d, 0, 128 + wm*64 + m*16 + lr, kk);
    STAGE((t+2) & MSK, 0, 0);
    __builtin_amdgcn_s_barrier();
    asm volatile("s_waitcnt lgkmcnt(0)" ::: "memory");
    __builtin_amdgcn_sched_barrier(0);
    __builtin_amdgcn_s_setprio(1);
#pragma unroll
    for (int m = 0; m < 4; ++m)
#pragma unroll
      for (int nn = 0; nn < 2; ++nn)
#pragma unroll
        for (int kk = 0; kk < 2; ++kk)
          acc[4+m][2+nn] = __builtin_amdgcn_mfma_f32_16x16x32_bf16(a[m][kk], b[nn][kk], acc[4+m][2+nn], 0, 0, 0);
    __builtin_amdgcn_s_setprio(0);
    __builtin_amdgcn_sched_barrier(0);
    __builtin_amdgcn_s_barrier();
    STAGE((t+2) & MSK, 1, 1);
    __builtin_amdgcn_s_barrier();
    asm volatile("s_waitcnt lgkmcnt(0)" ::: "memory");
    __builtin_amdgcn_sched_barrier(0);
    __builtin_amdgcn_s_setprio(1);
#pragma unroll
    for (int m = 0; m < 4; ++m)
#pragma unroll
      for (int nn = 0; nn < 2; ++nn)
#pragma unroll
        for (int kk = 0; kk < 2; ++kk)
          acc[4+m][nn] = __builtin_amdgcn_mfma_f32_16x16x32_bf16(a[m][kk], b0h[nn][kk], acc[4+m][nn], 0, 0, 0);
    __builtin_amdgcn_s_setprio(0);
    __builtin_amdgcn_sched_barrier(0);
    asm volatile("s_waitcnt vmcnt(6)" ::: "memory");
    __builtin_amdgcn_s_barrier();
  }

  const int rl = (lane >> 4) << 2;
  if (ACT) {
#pragma unroll
    for (int mq = 0; mq < 2; ++mq)
#pragma unroll
      for (int m = 0; m < 4; ++m) {
        int rbase = mq*128 + wm*64 + m*16 + rl;
#pragma unroll
        for (int nq = 0; nq < 2; ++nq) {
          f32x4 h1 = acc[mq*4+m][nq*2], h3 = acc[mq*4+m][nq*2+1];
          int ucol = xt*128 + nq*64 + wn*16 + lr;
#pragma unroll
          for (int j = 0; j < 4; ++j) {
            int lrow = rbase + j;
            if (lrow < rv) {
              float v1 = h1[j];
              float uu = v1 / (1.f + __expf(-v1)) * h3[j];
              out[(size_t)(rowbase + brow + lrow) * IDIM + ucol] = f32_to_bf16(uu);
            }
          }
        }
      }
  } else {
#pragma unroll
    for (int mq = 0; mq < 2; ++mq)
#pragma unroll
      for (int m = 0; m < 4; ++m) {
        int rbase = mq*128 + wm*64 + m*16 + rl;
#pragma unroll
        for (int nq = 0; nq < 2; ++nq)
#pragma unroll
          for (int nn = 0; nn < 2; ++nn) {
            int col = xt*256 + nq*128 + wn*32 + nn*16 + lr;
            f32x4 v = acc[mq*4+m][nq*2+nn];
#pragma unroll
            for (int j = 0; j < 4; ++j) {
              int lrow = rbase + j;
              if (lrow < rv)
                out[(size_t)(rowbase + brow + lrow) * HDIM + col] = f32_to_bf16(v[j]);
            }
          }
      }
  }
}

// ---------------- combine: y[t] = sum_k w_k * oe[e_k][pos_k] + shared[t] ----------------
__global__ __launch_bounds__(256) void k_combine(const u16* __restrict__ oe,
                                                 const int* __restrict__ idx, const float* __restrict__ wts,
                                                 const int* __restrict__ pos, float* __restrict__ y) {
  int t = blockIdx.x;
  int h0 = threadIdx.x * 4;
  float a0 = 0, a1 = 0, a2 = 0, a3 = 0;
#pragma unroll
  for (int k = 0; k < KSEL; ++k) {
    int e = idx[t*KSEL + k];
    int p = pos[t*KSEL + k];
    if (p < CAPE) {
      float w = wts[t*KSEL + k];
      ushort4 v = *reinterpret_cast<const ushort4*>(oe + ((long)e * CAPE + p) * HDIM + h0);
      a0 += w * bf16_to_f32(v.x); a1 += w * bf16_to_f32(v.y);
      a2 += w * bf16_to_f32(v.z); a3 += w * bf16_to_f32(v.w);
    }
  }
  ushort4 s = *reinterpret_cast<const ushort4*>(oe + ((long)NEXP * CAPE + t) * HDIM + h0);
  a0 += bf16_to_f32(s.x); a1 += bf16_to_f32(s.y); a2 += bf16_to_f32(s.z); a3 += bf16_to_f32(s.w);
  float4 o2; o2.x = a0; o2.y = a1; o2.z = a2; o2.w = a3;
  reinterpret_cast<float4*>(y + (long)t * HDIM)[threadIdx.x] = o2;
}

extern "C" void kernel_launch(void* const* d_in, const int* in_sizes, int n_in,
                              void* d_out, int out_size, void* d_ws, size_t ws_size,
                              hipStream_t stream) {
  const float* x      = (const float*)d_in[0];
  const float* gate_w = (const float*)d_in[1];
  const float* w13    = (const float*)d_in[2];
  const float* w2     = (const float*)d_in[3];
  const float* sw1    = (const float*)d_in[4];
  const float* sw2    = (const float*)d_in[5];
  const float* sw3    = (const float*)d_in[6];
  float* y = (float*)d_out;

  char* base = (char*)d_ws;
  size_t off = 0;
  auto alloc = [&](size_t bytes) -> void* {
    void* p = base + off;
    off = (off + bytes + 255) & ~(size_t)255;
    return p;
  };
  u16* xb    = (u16*)alloc((size_t)T_TOK * HDIM * 2);
  u16* w2b   = (u16*)alloc((size_t)(NEXP + 1) * HDIM * IDIM * 2);
  u16* u_ws  = (u16*)alloc((size_t)NROW * IDIM * 2);
  u16* oe_ws = (u16*)alloc((size_t)NROW * HDIM * 2);
  int*   idx  = (int*)alloc((size_t)T_TOK * KSEL * 4);
  float* wts  = (float*)alloc((size_t)T_TOK * KSEL * 4);
  int*   pos  = (int*)alloc((size_t)T_TOK * KSEL * 4);
  int*   etok = (int*)alloc((size_t)NROW * 4);
  int*   cnts = (int*)alloc(256);
  int*   list = (int*)alloc(MAXTILE * 4);
  int*   tot  = (int*)alloc(64);
  int*   done = (int*)alloc(64);
  if (off > ws_size) return;

  // 1. gate (fp64 logits top-k + fused x->bf16); resets done[0]
  k_pre<<<dim3(128), dim3(256), 0, stream>>>(x, gate_w, idx, wts, xb, done);
  // 2. capacity assignment + work-list scheduler
  k_assign<<<dim3(NEXP + 1), dim3(1024), 0, stream>>>(idx, etok, pos, cnts, list, tot, done);
  // 3. GEMM1: B = w13 fp32 direct (reg-staged cvt in MFMA shadow); inactive blocks convert w2 -> bf16
  k_gemm1f<<<dim3(MAXWG + CVTWG), dim3(512), 0, stream>>>(
      xb, w13, sw1, sw3, u_ws, etok, cnts, list, tot,
      w2, sw2, w2b, (long)(NEXP + 1) * HDIM * IDIM / 8);
  // 4. GEMM2 (bf16 w2b)
  k_gemm8<IDIM, false, false><<<dim3(MAXWG), dim3(512), 0, stream>>>(
      u_ws, w2b, oe_ws, etok, cnts, list, tot);
  // 5. combine
  k_combine<<<dim3(T_TOK), dim3(256), 0, stream>>>(oe_ws, idx, wts, pos, y);
}

// Round 9
// 301.598 us; speedup vs baseline: 1.0225x; 1.0225x over previous
//
#include <hip/hip_runtime.h>

typedef unsigned short u16;
typedef unsigned int u32;
typedef float f32x4 __attribute__((ext_vector_type(4)));
typedef __bf16 bf16x8 __attribute__((ext_vector_type(8)));

#define T_TOK 4096
#define HDIM 1024
#define IDIM 512
#define NEXP 32
#define KSEL 8
#define CAPE 2048
#define NROW (NEXP*CAPE + T_TOK)   // 69632 rows total (experts + shared)
#define MAXTILE 544                // 32 experts * 16 y-tiles(128) + 32 shared tiles
#define MAXWG  (MAXTILE*8)         // 4352
#define CVTWG  512                 // guaranteed converter blocks appended to GEMM1

__device__ __forceinline__ u16 f32_to_bf16(float f) {
  u32 x = __float_as_uint(f);
  u32 r = (x + 0x7FFFu + ((x >> 16) & 1u)) >> 16;   // RNE; inputs finite
  return (u16)r;
}
__device__ __forceinline__ float bf16_to_f32(u16 u) {
  return __uint_as_float(((u32)u) << 16);
}

// ---------------- k_pre: gate (blocks 0..127) ∪ w13 interleave convert (blocks 128..2175) ----------------
__global__ __launch_bounds__(256) void k_pre(const float* __restrict__ x, const float* __restrict__ gw,
                                             const float* __restrict__ w13,
                                             const float* __restrict__ sw1, const float* __restrict__ sw3,
                                             int* __restrict__ idx, float* __restrict__ wts,
                                             u16* __restrict__ xb, u16* __restrict__ w13b,
                                             int* __restrict__ done) {
  const int tid = threadIdx.x;
  if (blockIdx.x >= 128) {
    const long n8 = (long)(NEXP + 1) * 1024 * 128;
    const long stride = (long)(2176 - 128) * 256;
    for (long j = (long)(blockIdx.x - 128) * 256 + tid; j < n8; j += stride) {
      int e   = (int)(j >> 17);
      int rem = (int)(j & 131071);
      int rowd = rem >> 7;
      int c8   = rem & 127;
      int c = rowd >> 4, cw = rowd & 15;
      int srow = (c >> 1) * 16 + cw;
      int sel = c & 1;
      const float* s;
      if (e < NEXP) s = w13 + (size_t)e * (2 * IDIM * HDIM) + (size_t)(sel * IDIM + srow) * HDIM + c8 * 8;
      else          s = (sel ? sw3 : sw1) + (size_t)srow * HDIM + c8 * 8;
      float4 a = reinterpret_cast<const float4*>(s)[0];
      float4 b = reinterpret_cast<const float4*>(s)[1];
      ushort4 lo, hi;
      lo.x=f32_to_bf16(a.x); lo.y=f32_to_bf16(a.y); lo.z=f32_to_bf16(a.z); lo.w=f32_to_bf16(a.w);
      hi.x=f32_to_bf16(b.x); hi.y=f32_to_bf16(b.y); hi.z=f32_to_bf16(b.z); hi.w=f32_to_bf16(b.w);
      u16* d = w13b + ((size_t)e * 1024 + rowd) * HDIM + c8 * 8;
      reinterpret_cast<ushort4*>(d)[0] = lo;
      reinterpret_cast<ushort4*>(d)[1] = hi;
    }
    return;
  }
  // ---- gate path ----
  __shared__ float xs[32][129];
  __shared__ float gs_[32][129];
  __shared__ double sc[32][32];
  const int t0 = blockIdx.x * 32;
  const int tl = tid & 31, g = tid >> 5;
  if (blockIdx.x == 0 && tid == 0) done[0] = 0;   // reset rendezvous for k_assign
  double acc0 = 0, acc1 = 0, acc2 = 0, acc3 = 0;
  for (int k0 = 0; k0 < HDIM; k0 += 128) {
#pragma unroll
    for (int q = 0; q < 4; ++q) {
      int f = tid + 256 * q;
      int row = f >> 5, c4 = (f & 31) * 4;
      float4 v = *reinterpret_cast<const float4*>(x + (long)(t0 + row) * HDIM + k0 + c4);
      xs[row][c4+0]=v.x; xs[row][c4+1]=v.y; xs[row][c4+2]=v.z; xs[row][c4+3]=v.w;
      ushort4 xv; xv.x=f32_to_bf16(v.x); xv.y=f32_to_bf16(v.y); xv.z=f32_to_bf16(v.z); xv.w=f32_to_bf16(v.w);
      *reinterpret_cast<ushort4*>(xb + (long)(t0 + row) * HDIM + k0 + c4) = xv;   // fused x convert
      float4 w = *reinterpret_cast<const float4*>(gw + (long)row * HDIM + k0 + c4);
      gs_[row][c4+0]=w.x; gs_[row][c4+1]=w.y; gs_[row][c4+2]=w.z; gs_[row][c4+3]=w.w;
    }
    __syncthreads();
#pragma unroll 4
    for (int kk = 0; kk < 128; ++kk) {
      double xv = (double)xs[tl][kk];
      acc0 += xv * (double)gs_[g     ][kk];
      acc1 += xv * (double)gs_[g +  8][kk];
      acc2 += xv * (double)gs_[g + 16][kk];
      acc3 += xv * (double)gs_[g + 24][kk];
    }
    __syncthreads();
  }
  sc[tl][g     ] = acc0;   // raw logits; sigmoid monotonic -> same top-k order
  sc[tl][g +  8] = acc1;
  sc[tl][g + 16] = acc2;
  sc[tl][g + 24] = acc3;
  __syncthreads();
  if (tid < 32) {
    int t = t0 + tid;
    double gsc[8];
#pragma unroll
    for (int gg = 0; gg < 8; ++gg) {
      double mx = sc[tid][4*gg];
#pragma unroll
      for (int j = 1; j < 4; ++j) mx = fmax(mx, sc[tid][4*gg + j]);
      gsc[gg] = mx;
    }
    unsigned gmask = 0;
    for (int it = 0; it < 4; ++it) {          // top-4 groups, strict >, first index wins
      double best = -1e300; int bi = 0;
      for (int gg = 0; gg < 8; ++gg)
        if (!((gmask >> gg) & 1) && gsc[gg] > best) { best = gsc[gg]; bi = gg; }
      gmask |= 1u << bi;
    }
    unsigned emask = 0; int ei[KSEL]; double ew[KSEL]; double wsum = 0;
    for (int it = 0; it < KSEL; ++it) {       // top-8 experts on logits
      double best = -1e300; int bi = 0;
      for (int e = 0; e < NEXP; ++e)
        if (((gmask >> (e >> 2)) & 1) && !((emask >> e) & 1)) {
          double v = sc[tid][e];
          if (v > best) { best = v; bi = e; }
        }
      emask |= 1u << bi; ei[it] = bi;
      double sg = 1.0 / (1.0 + exp(-best));   // sigmoid only for selected
      ew[it] = sg; wsum += sg;
    }
    double s = 2.5 / (wsum + 1e-20);
    for (int k = 0; k < KSEL; ++k) { idx[t*KSEL + k] = ei[k]; wts[t*KSEL + k] = (float)(ew[k] * s); }
  }
}

// ---------------- capacity assignment (ballot-scan) + inline tile scheduler (128-row tiles) ----------------
__global__ __launch_bounds__(1024) void k_assign(const int* __restrict__ idx,
                                                 int* __restrict__ etok, int* __restrict__ pos,
                                                 int* __restrict__ cnts,
                                                 int* __restrict__ list, int* __restrict__ tot,
                                                 int* __restrict__ done) {
  const int e = blockIdx.x;
  const int tid = threadIdx.x;
  int base = 0;
  if (e == NEXP) {
    for (int t = tid; t < T_TOK; t += 1024) etok[NEXP*CAPE + t] = t;
    base = T_TOK;
  } else {
    __shared__ int wbase[17];
    const int wid = tid >> 6, lane = tid & 63;
    for (int c = 0; c < T_TOK / 1024; ++c) {
      int t = c * 1024 + tid;
      int found = -1;
#pragma unroll
      for (int k = 0; k < KSEL; ++k) if (idx[t*KSEL + k] == e) found = k;
      unsigned long long mask = __ballot(found >= 0);
      int myrank = __popcll(mask & ((1ull << lane) - 1ull));
      __syncthreads();
      if (lane == 0) wbase[wid] = __popcll(mask);
      __syncthreads();
      if (tid == 0) {
        int run = 0;
#pragma unroll
        for (int w = 0; w < 16; ++w) { int v = wbase[w]; wbase[w] = run; run += v; }
        wbase[16] = run;
      }
      __syncthreads();
      if (found >= 0) {
        int slot = base + wbase[wid] + myrank;
        pos[t*KSEL + found] = slot;
        if (slot < CAPE) etok[e*CAPE + slot] = t;
      }
      base += wbase[16];
      __syncthreads();
    }
    base = min(base, CAPE);
  }
  if (tid == 0) {
    cnts[e] = base;
    __threadfence();
    if (atomicAdd(done, 1) == NEXP) {          // last finisher builds the compact work list
      __threadfence();
      int run = 0;
      for (int ee = 0; ee <= NEXP; ++ee) {
        int c = atomicAdd(&cnts[ee], 0);       // device-scope read
        int nt = (c + 127) >> 7;               // 128-row tiles
        for (int i = 0; i < nt; ++i) list[run + i] = ee * 32 + i;
        run += nt;
      }
      tot[0] = run * 8;                        // 8 x-tiles of 128 cols each
    }
  }
}

// ---------------- grouped GEMM: 128x128 tile, BK=64, m97 structure (32 KiB LDS, ~5 blocks/CU TLP) ----------
// r1-proven inner (stage -> barrier -> compute; cross-block TLP hides the vmcnt(0) drain) +
// r3's compact list + m204 bijective XCD swizzle. Blocks beyond the active prefix run the
// w2 fp32->bf16 converter service (GEMM1 only).

#define GLDS(gp, lp) __builtin_amdgcn_global_load_lds( \
    (const __attribute__((address_space(1))) void*)(gp), \
    (__attribute__((address_space(3))) void*)(lp), 16, 0, 0)

template<int KDIM, bool GATHER, bool ACT>
__global__ __launch_bounds__(256) void k_gemm(const u16* __restrict__ A, const u16* __restrict__ Ball,
                                              u16* __restrict__ out,
                                              const int* __restrict__ etok, const int* __restrict__ cnts,
                                              const int* __restrict__ list, const int* __restrict__ tot,
                                              const float* __restrict__ cvsrc, const float* __restrict__ cvsrc2,
                                              u16* __restrict__ cvdst, long cvt_n8) {
  __shared__ u16 lA[128 * 64];
  __shared__ u16 lB[128 * 64];
  const int n = tot[0];                 // active wg count (8 * tiles)
  const int bid0 = blockIdx.x;
  const int tid = threadIdx.x;
  if (bid0 >= n) {
    // ---- converter service: stream cvsrc (E experts) + cvsrc2 (shared) -> cvdst bf16 ----
    if (cvt_n8 > 0) {
      const long nb = (long)gridDim.x - n;
      const long stride = nb * 256;
      for (long j = (long)(bid0 - n) * 256 + tid; j < cvt_n8; j += stride) {
        int e   = (int)(j >> 16);                    // 65536 chunks per expert (H*I/8)
        int rem = (int)(j & 65535);
        const float* s = ((e < NEXP) ? cvsrc + ((size_t)e << 19) : cvsrc2) + (size_t)rem * 8;
        float4 a = reinterpret_cast<const float4*>(s)[0];
        float4 b = reinterpret_cast<const float4*>(s)[1];
        ushort4 lo, hi;
        lo.x=f32_to_bf16(a.x); lo.y=f32_to_bf16(a.y); lo.z=f32_to_bf16(a.z); lo.w=f32_to_bf16(a.w);
        hi.x=f32_to_bf16(b.x); hi.y=f32_to_bf16(b.y); hi.z=f32_to_bf16(b.z); hi.w=f32_to_bf16(b.w);
        u16* d = cvdst + ((size_t)e << 19) + (size_t)rem * 8;
        reinterpret_cast<ushort4*>(d)[0] = lo;
        reinterpret_cast<ushort4*>(d)[1] = hi;
      }
    }
    return;
  }
  // m204 bijective XCD swizzle over [0,n): same-expert tiles stay contiguous within an XCD chunk
  const int q = n >> 3, r = n & 7, xc = bid0 & 7, o = bid0 >> 3;
  const int wg = (xc < r ? xc * (q + 1) : r * (q + 1) + (xc - r) * q) + o;
  const int item = list[wg >> 3];
  const int e = item >> 5, yt = item & 31, xt = wg & 7;

  const int cnt = cnts[e];
  const int brow = yt * 128;
  const int rv = min(128, cnt - brow);
  const long rowbase = (long)e * CAPE;
  const u16* Bexp = Ball + (size_t)e * (size_t)(1024 * KDIM);

  const int wave = tid >> 6, lane = tid & 63;
  const int wr = wave >> 1, wc = wave & 1;

  // staging source pointers: chunk ci = (wave*4+c)*64+lane; row=ci>>3, slot=ci&7; pre-swizzled source
  const u16* pa[4]; const u16* pb[4];
#pragma unroll
  for (int c = 0; c < 4; ++c) {
    int ci = (wave*4 + c) * 64 + lane;
    int row = ci >> 3, slot = ci & 7;
    int sl = slot ^ (row & 7);
    long arow;
    if (GATHER) arow = (row < rv) ? (long)etok[rowbase + brow + row] : 0L;
    else        arow = rowbase + brow + row;
    pa[c] = A + arow * KDIM + sl * 8;
    pb[c] = Bexp + ((long)(xt*128 + row)) * KDIM + sl * 8;
  }

  f32x4 zero = {0.f, 0.f, 0.f, 0.f};
  f32x4 acc[4][4];
#pragma unroll
  for (int m = 0; m < 4; ++m)
#pragma unroll
    for (int nn = 0; nn < 4; ++nn) acc[m][nn] = zero;

  for (int kt = 0; kt < KDIM / 64; ++kt) {
#pragma unroll
    for (int c = 0; c < 4; ++c) GLDS(pa[c] + kt*64, lA + (wave*4 + c) * 512);
#pragma unroll
    for (int c = 0; c < 4; ++c) GLDS(pb[c] + kt*64, lB + (wave*4 + c) * 512);
    __syncthreads();                                   // compiler drains vmcnt before barrier
#pragma unroll
    for (int kk = 0; kk < 2; ++kk) {
      bf16x8 af[4], bfr[4];
#pragma unroll
      for (int m = 0; m < 4; ++m) {
        int rr = wr*64 + m*16 + (lane & 15);
        int bc = (kk*64 + ((lane >> 4) * 16)) ^ ((rr & 7) << 4);
        af[m] = *reinterpret_cast<const bf16x8*>(reinterpret_cast<const char*>(lA) + rr*128 + bc);
      }
#pragma unroll
      for (int nn = 0; nn < 4; ++nn) {
        int rr = wc*64 + nn*16 + (lane & 15);
        int bc = (kk*64 + ((lane >> 4) * 16)) ^ ((rr & 7) << 4);
        bfr[nn] = *reinterpret_cast<const bf16x8*>(reinterpret_cast<const char*>(lB) + rr*128 + bc);
      }
#pragma unroll
      for (int m = 0; m < 4; ++m)
#pragma unroll
        for (int nn = 0; nn < 4; ++nn)
          acc[m][nn] = __builtin_amdgcn_mfma_f32_16x16x32_bf16(af[m], bfr[nn], acc[m][nn], 0, 0, 0);
    }
    __syncthreads();
  }

  // epilogue: C/D map col=lane&15, row=(lane>>4)*4+reg  [verified m89]
  if (ACT) {
#pragma unroll
    for (int m = 0; m < 4; ++m) {
#pragma unroll
      for (int qq = 0; qq < 2; ++qq) {
        f32x4 h1 = acc[m][2*qq], h3 = acc[m][2*qq + 1];
        int ucol = xt*64 + wc*32 + qq*16 + (lane & 15);
#pragma unroll
        for (int j = 0; j < 4; ++j) {
          int lrow = wr*64 + m*16 + ((lane >> 4) << 2) + j;
          if (lrow < rv) {
            float v1 = h1[j];
            float uu = v1 / (1.f + __expf(-v1)) * h3[j];   // silu(h1)*h3
            out[(size_t)(rowbase + brow + lrow) * IDIM + ucol] = f32_to_bf16(uu);
          }
        }
      }
    }
  } else {
#pragma unroll
    for (int m = 0; m < 4; ++m) {
#pragma unroll
      for (int nn = 0; nn < 4; ++nn) {
        int col = xt*128 + wc*64 + nn*16 + (lane & 15);
#pragma unroll
        for (int j = 0; j < 4; ++j) {
          int lrow = wr*64 + m*16 + ((lane >> 4) << 2) + j;
          if (lrow < rv)
            out[(size_t)(rowbase + brow + lrow) * HDIM + col] = f32_to_bf16(acc[m][nn][j]);
        }
      }
    }
  }
}

// ---------------- combine: y[t] = sum_k w_k * oe[e_k][pos_k] + shared[t] ----------------
__global__ __launch_bounds__(256) void k_combine(const u16* __restrict__ oe,
                                                 const int* __restrict__ idx, const float* __restrict__ wts,
                                                 const int* __restrict__ pos, float* __restrict__ y) {
  int t = blockIdx.x;
  int h0 = threadIdx.x * 4;
  float a0 = 0, a1 = 0, a2 = 0, a3 = 0;
#pragma unroll
  for (int k = 0; k < KSEL; ++k) {
    int e = idx[t*KSEL + k];
    int p = pos[t*KSEL + k];
    if (p < CAPE) {
      float w = wts[t*KSEL + k];
      ushort4 v = *reinterpret_cast<const ushort4*>(oe + ((long)e * CAPE + p) * HDIM + h0);
      a0 += w * bf16_to_f32(v.x); a1 += w * bf16_to_f32(v.y);
      a2 += w * bf16_to_f32(v.z); a3 += w * bf16_to_f32(v.w);
    }
  }
  ushort4 s = *reinterpret_cast<const ushort4*>(oe + ((long)NEXP * CAPE + t) * HDIM + h0);
  a0 += bf16_to_f32(s.x); a1 += bf16_to_f32(s.y); a2 += bf16_to_f32(s.z); a3 += bf16_to_f32(s.w);
  float4 o2; o2.x = a0; o2.y = a1; o2.z = a2; o2.w = a3;
  reinterpret_cast<float4*>(y + (long)t * HDIM)[threadIdx.x] = o2;
}

extern "C" void kernel_launch(void* const* d_in, const int* in_sizes, int n_in,
                              void* d_out, int out_size, void* d_ws, size_t ws_size,
                              hipStream_t stream) {
  const float* x      = (const float*)d_in[0];
  const float* gate_w = (const float*)d_in[1];
  const float* w13    = (const float*)d_in[2];
  const float* w2     = (const float*)d_in[3];
  const float* sw1    = (const float*)d_in[4];
  const float* sw2    = (const float*)d_in[5];
  const float* sw3    = (const float*)d_in[6];
  float* y = (float*)d_out;

  char* base = (char*)d_ws;
  size_t off = 0;
  auto alloc = [&](size_t bytes) -> void* {
    void* p = base + off;
    off = (off + bytes + 255) & ~(size_t)255;
    return p;
  };
  u16* xb    = (u16*)alloc((size_t)T_TOK * HDIM * 2);
  u16* w13b  = (u16*)alloc((size_t)(NEXP + 1) * 2 * IDIM * HDIM * 2);
  u16* w2b   = (u16*)alloc((size_t)(NEXP + 1) * HDIM * IDIM * 2);
  u16* u_ws  = (u16*)alloc((size_t)NROW * IDIM * 2);
  u16* oe_ws = (u16*)alloc((size_t)NROW * HDIM * 2);
  int*   idx  = (int*)alloc((size_t)T_TOK * KSEL * 4);
  float* wts  = (float*)alloc((size_t)T_TOK * KSEL * 4);
  int*   pos  = (int*)alloc((size_t)T_TOK * KSEL * 4);
  int*   etok = (int*)alloc((size_t)NROW * 4);
  int*   cnts = (int*)alloc(256);
  int*   list = (int*)alloc(MAXTILE * 4);
  int*   tot  = (int*)alloc(64);
  int*   done = (int*)alloc(64);
  if (off > ws_size) return;

  // 1. gate (128 blocks) || w13+sw1/sw3 -> bf16 interleave convert (2048 blocks)
  k_pre<<<dim3(2176), dim3(256), 0, stream>>>(x, gate_w, w13, sw1, sw3, idx, wts, xb, w13b, done);
  // 2. capacity assignment + 128-row-tile work-list scheduler
  k_assign<<<dim3(NEXP + 1), dim3(1024), 0, stream>>>(idx, etok, pos, cnts, list, tot, done);
  // 3. GEMM1 (bf16 w13b, 128^2 tiles, ~5 blocks/CU); inactive blocks convert w2+sw2 -> w2b
  k_gemm<HDIM, true,  true ><<<dim3(MAXWG + CVTWG), dim3(256), 0, stream>>>(
      xb, w13b, u_ws, etok, cnts, list, tot,
      w2, sw2, w2b, (long)(NEXP + 1) * HDIM * IDIM / 8);
  // 4. GEMM2 (bf16 w2b)
  k_gemm<IDIM, false, false><<<dim3(MAXWG), dim3(256), 0, stream>>>(
      u_ws, w2b, oe_ws, etok, cnts, list, tot,
      nullptr, nullptr, nullptr, 0L);
  // 5. combine
  k_combine<<<dim3(T_TOK), dim3(256), 0, stream>>>(oe_ws, idx, wts, pos, y);
}

// Round 10
// 279.443 us; speedup vs baseline: 1.1036x; 1.0793x over previous
//
#include <hip/hip_runtime.h>

typedef unsigned short u16;
typedef unsigned int u32;
typedef float f32x4 __attribute__((ext_vector_type(4)));
typedef __bf16 bf16x8 __attribute__((ext_vector_type(8)));

#define T_TOK 4096
#define HDIM 1024
#define IDIM 512
#define NEXP 32
#define KSEL 8
#define CAPE 2048
#define NROW (NEXP*CAPE + T_TOK)   // 69632 rows total (experts + shared)
#define MAXTILE 528                // 33 experts * 16 y-tiles max
#define MAXWG  (MAXTILE*4)         // 2112
#define CVTWG  512                 // guaranteed converter blocks appended to GEMM1

__device__ __forceinline__ u16 f32_to_bf16(float f) {
  u32 x = __float_as_uint(f);
  u32 r = (x + 0x7FFFu + ((x >> 16) & 1u)) >> 16;   // RNE; inputs finite
  return (u16)r;
}
__device__ __forceinline__ float bf16_to_f32(u16 u) {
  return __uint_as_float(((u32)u) << 16);
}

// ---------------- k_pre (1024 thr): gate (0..127) ∪ assign (128..160, gated) ∪ w13 cvt (161..2208) ----
// Gate: one (token, expert) fp64 dot product PER THREAD (32x32 = 1024); top-k on logits (sigmoid
// monotonic), sigmoid only for the 8 winners; fused x->bf16; RELEASE-increment done[0].
// Assign: r5's 1024-thread ballot-scan verbatim, spin-gated on done[0]==128 (+ACQUIRE); last
// finisher (done[1]) builds the compact 256-row tile list. Convert: w13(+sw1/sw3) -> bf16
// with the 16-row w1/w3 interleave. done[] reset via hipMemsetAsync (no in-kernel reset race).
// Deadlock-free for any dispatch order: converters never wait; assign waits only on gates.
__global__ __launch_bounds__(1024) void k_pre(const float* __restrict__ x, const float* __restrict__ gw,
                                              const float* __restrict__ w13,
                                              const float* __restrict__ sw1, const float* __restrict__ sw3,
                                              int* __restrict__ idx, float* __restrict__ wts,
                                              u16* __restrict__ xb, u16* __restrict__ w13b,
                                              int* __restrict__ etok, int* __restrict__ pos,
                                              int* __restrict__ cnts,
                                              int* __restrict__ list, int* __restrict__ tot,
                                              int* __restrict__ done) {
  const int tid = threadIdx.x;
  if (blockIdx.x >= 161) {
    // ---- w13 convert: chunk j of 8 f32; dest row rd: c=rd>>4, even c -> w1 rows (c>>1)*16.., odd -> w3
    const long n8 = (long)(NEXP + 1) * 1024 * 128;
    const long stride = (long)(2209 - 161) * 1024;
    for (long j = (long)(blockIdx.x - 161) * 1024 + tid; j < n8; j += stride) {
      int e   = (int)(j >> 17);
      int rem = (int)(j & 131071);
      int rowd = rem >> 7;
      int c8   = rem & 127;
      int c = rowd >> 4, cw = rowd & 15;
      int srow = (c >> 1) * 16 + cw;
      int sel = c & 1;
      const float* s;
      if (e < NEXP) s = w13 + (size_t)e * (2 * IDIM * HDIM) + (size_t)(sel * IDIM + srow) * HDIM + c8 * 8;
      else          s = (sel ? sw3 : sw1) + (size_t)srow * HDIM + c8 * 8;
      float4 a = reinterpret_cast<const float4*>(s)[0];
      float4 b = reinterpret_cast<const float4*>(s)[1];
      ushort4 lo, hi;
      lo.x=f32_to_bf16(a.x); lo.y=f32_to_bf16(a.y); lo.z=f32_to_bf16(a.z); lo.w=f32_to_bf16(a.w);
      hi.x=f32_to_bf16(b.x); hi.y=f32_to_bf16(b.y); hi.z=f32_to_bf16(b.z); hi.w=f32_to_bf16(b.w);
      u16* d = w13b + ((size_t)e * 1024 + rowd) * HDIM + c8 * 8;
      reinterpret_cast<ushort4*>(d)[0] = lo;
      reinterpret_cast<ushort4*>(d)[1] = hi;
    }
    return;
  }
  if (blockIdx.x >= 128) {
    // ---- assign path (r5 k_assign verbatim, gated on all 128 gate blocks) ----
    const int e = blockIdx.x - 128;
    if (tid == 0) {
      while (__hip_atomic_load(&done[0], __ATOMIC_RELAXED, __HIP_MEMORY_SCOPE_AGENT) < 128)
        __builtin_amdgcn_s_sleep(2);
      (void)__hip_atomic_load(&done[0], __ATOMIC_ACQUIRE, __HIP_MEMORY_SCOPE_AGENT);  // inv stale L1/L2
    }
    __syncthreads();
    int base = 0;
    if (e == NEXP) {
      for (int t = tid; t < T_TOK; t += 1024) etok[NEXP*CAPE + t] = t;
      base = T_TOK;
    } else {
      __shared__ int wbase[17];
      const int wid = tid >> 6, lane = tid & 63;
      for (int c = 0; c < T_TOK / 1024; ++c) {
        int t = c * 1024 + tid;
        int found = -1;
#pragma unroll
        for (int k = 0; k < KSEL; ++k) if (idx[t*KSEL + k] == e) found = k;
        unsigned long long mask = __ballot(found >= 0);
        int myrank = __popcll(mask & ((1ull << lane) - 1ull));
        __syncthreads();
        if (lane == 0) wbase[wid] = __popcll(mask);
        __syncthreads();
        if (tid == 0) {
          int run = 0;
#pragma unroll
          for (int w = 0; w < 16; ++w) { int v = wbase[w]; wbase[w] = run; run += v; }
          wbase[16] = run;
        }
        __syncthreads();
        if (found >= 0) {
          int slot = base + wbase[wid] + myrank;
          pos[t*KSEL + found] = slot;
          if (slot < CAPE) etok[e*CAPE + slot] = t;
        }
        base += wbase[16];
        __syncthreads();
      }
      base = min(base, CAPE);
    }
    if (tid == 0) {
      cnts[e] = base;
      __threadfence();
      if (__hip_atomic_fetch_add(&done[1], 1, __ATOMIC_RELEASE, __HIP_MEMORY_SCOPE_AGENT) == NEXP) {
        __threadfence();
        int run = 0;
        for (int ee = 0; ee <= NEXP; ++ee) {
          int c = atomicAdd(&cnts[ee], 0);       // device-scope read
          int nt = (c + 255) >> 8;
          for (int i = 0; i < nt; ++i) list[run + i] = ee * 16 + i;
          run += nt;
        }
        tot[0] = run * 4;
      }
    }
    return;
  }
  // ---- gate path: thread (tl, g) computes logit[token t0+tl][expert g] in fp64 ----
  __shared__ float xs[32][129];
  __shared__ float gs_[32][129];
  __shared__ double sc[32][32];
  const int t0 = blockIdx.x * 32;
  const int tl = tid & 31, g = tid >> 5;
  const int row = tid >> 5, c4 = (tid & 31) * 4;     // staging: 32 rows x 32 float4
  double acc = 0;
  for (int k0 = 0; k0 < HDIM; k0 += 128) {
    float4 v = *reinterpret_cast<const float4*>(x + (long)(t0 + row) * HDIM + k0 + c4);
    xs[row][c4+0]=v.x; xs[row][c4+1]=v.y; xs[row][c4+2]=v.z; xs[row][c4+3]=v.w;
    ushort4 xv; xv.x=f32_to_bf16(v.x); xv.y=f32_to_bf16(v.y); xv.z=f32_to_bf16(v.z); xv.w=f32_to_bf16(v.w);
    *reinterpret_cast<ushort4*>(xb + (long)(t0 + row) * HDIM + k0 + c4) = xv;   // fused x convert
    float4 w = *reinterpret_cast<const float4*>(gw + (long)row * HDIM + k0 + c4);
    gs_[row][c4+0]=w.x; gs_[row][c4+1]=w.y; gs_[row][c4+2]=w.z; gs_[row][c4+3]=w.w;
    __syncthreads();
#pragma unroll 4
    for (int kk = 0; kk < 128; ++kk)
      acc += (double)xs[tl][kk] * (double)gs_[g][kk];
    __syncthreads();
  }
  sc[tl][g] = acc;          // raw logits; sigmoid monotonic -> same top-k order
  __syncthreads();
  if (tid < 32) {
    int t = t0 + tid;
    double gsc[8];
#pragma unroll
    for (int gg = 0; gg < 8; ++gg) {
      double mx = sc[tid][4*gg];
#pragma unroll
      for (int j = 1; j < 4; ++j) mx = fmax(mx, sc[tid][4*gg + j]);
      gsc[gg] = mx;
    }
    unsigned gmask = 0;
    for (int it = 0; it < 4; ++it) {          // top-4 groups, strict >, first index wins
      double best = -1e300; int bi = 0;
      for (int gg = 0; gg < 8; ++gg)
        if (!((gmask >> gg) & 1) && gsc[gg] > best) { best = gsc[gg]; bi = gg; }
      gmask |= 1u << bi;
    }
    unsigned emask = 0; int ei[KSEL]; double ew[KSEL]; double wsum = 0;
    for (int it = 0; it < KSEL; ++it) {       // top-8 experts on logits
      double best = -1e300; int bi = 0;
      for (int e = 0; e < NEXP; ++e)
        if (((gmask >> (e >> 2)) & 1) && !((emask >> e) & 1)) {
          double v = sc[tid][e];
          if (v > best) { best = v; bi = e; }
        }
      emask |= 1u << bi; ei[it] = bi;
      double sg = 1.0 / (1.0 + exp(-best));   // sigmoid only for selected
      ew[it] = sg; wsum += sg;
    }
    double s = 2.5 / (wsum + 1e-20);
    for (int k = 0; k < KSEL; ++k) { idx[t*KSEL + k] = ei[k]; wts[t*KSEL + k] = (float)(ew[k] * s); }
  }
  __syncthreads();          // all idx/wts stores issued before the release
  if (tid == 0) {
    __threadfence();
    __hip_atomic_fetch_add(&done[0], 1, __ATOMIC_RELEASE, __HIP_MEMORY_SCOPE_AGENT);
  }
}

// ---------------- grouped GEMM: 256x256 tile, BK=64, 8-phase counted-vmcnt schedule (r5 verbatim) ------
// T1 bijective XCD swizzle over active prefix + T2 XOR LDS swizzle + T3/T4 8-phase counted
// vmcnt(6) + T5 setprio. Blocks beyond the active prefix run the fp32->bf16 converter for the
// NEXT GEMM's B (w2/sw2) instead of exiting (cvt_n8>0 only on GEMM1).

#define GLDS(gp, lp) __builtin_amdgcn_global_load_lds( \
    (const __attribute__((address_space(1))) void*)(gp), \
    (__attribute__((address_space(3))) void*)(lp), 16, 0, 0)

template<int KDIM, bool GATHER, bool ACT>
__global__ __launch_bounds__(512, 2) void k_gemm8(const u16* __restrict__ A, const u16* __restrict__ Ball,
                                                  u16* __restrict__ out,
                                                  const int* __restrict__ etok, const int* __restrict__ cnts,
                                                  const int* __restrict__ list, const int* __restrict__ tot,
                                                  const float* __restrict__ cvsrc, const float* __restrict__ cvsrc2,
                                                  u16* __restrict__ cvdst, long cvt_n8) {
  constexpr int NT = KDIM / 64;
  constexpr int MSK = NT - 1;
  __shared__ u16 lds[65536];            // [dbuf 2][op 2][256*64], 128 KiB

  const int n = tot[0];                 // active wg count (4 * tiles)
  const int bid0 = blockIdx.x;
  const int tid = threadIdx.x;
  if (bid0 >= n) {
    if (cvt_n8 > 0) {
      const long nb = (long)gridDim.x - n;
      const long stride = nb * 512;
      for (long j = (long)(bid0 - n) * 512 + tid; j < cvt_n8; j += stride) {
        int e   = (int)(j >> 16);                    // 65536 chunks per expert (H*I/8)
        int rem = (int)(j & 65535);
        const float* s = ((e < NEXP) ? cvsrc + ((size_t)e << 19) : cvsrc2) + (size_t)rem * 8;
        float4 a = reinterpret_cast<const float4*>(s)[0];
        float4 b = reinterpret_cast<const float4*>(s)[1];
        ushort4 lo, hi;
        lo.x=f32_to_bf16(a.x); lo.y=f32_to_bf16(a.y); lo.z=f32_to_bf16(a.z); lo.w=f32_to_bf16(a.w);
        hi.x=f32_to_bf16(b.x); hi.y=f32_to_bf16(b.y); hi.z=f32_to_bf16(b.z); hi.w=f32_to_bf16(b.w);
        u16* d = cvdst + ((size_t)e << 19) + (size_t)rem * 8;
        reinterpret_cast<ushort4*>(d)[0] = lo;
        reinterpret_cast<ushort4*>(d)[1] = hi;
      }
    }
    return;
  }
  // m204 bijective XCD swizzle over [0,n)
  const int q = n >> 3, r = n & 7, xc = bid0 & 7, o = bid0 >> 3;
  const int wg = (xc < r ? xc * (q + 1) : r * (q + 1) + (xc - r) * q) + o;
  const int item = list[wg >> 2];
  const int e = item >> 4, yt = item & 15, xt = wg & 3;

  const int cnt = cnts[e];
  const int brow = yt * 256;
  const int rv = min(256, cnt - brow);
  const long rowbase = (long)e * CAPE;
  const u16* Bexp = Ball + (size_t)e * (size_t)(1024 * KDIM);

  const int wave = tid >> 6, lane = tid & 63;
  const int wm = wave >> 2, wn = wave & 3;
  const int lr = lane & 15;
  const int lk = (lane >> 4) * 16;      // byte offset of this lane's K-slot

  const u16* pa[4]; const u16* pb[4];
#pragma unroll
  for (int j = 0; j < 4; ++j) {
    int row = j*64 + (tid >> 3);
    int sl = (tid & 7) ^ (row & 7);                  // pre-swizzled source chunk
    long arow;
    if (GATHER) arow = (row < rv) ? (long)etok[rowbase + brow + row] : 0L;
    else        arow = rowbase + brow + row;
    pa[j] = A + arow * KDIM + sl * 8;
    pb[j] = Bexp + ((long)(xt*256 + row)) * KDIM + sl * 8;
  }

  auto STAGE = [&](int st, int op, int h) {
    int dbase = (st & 1) * 32768 + op * 16384;
    const u16* const* pp = op ? pb : pa;
#pragma unroll
    for (int s = 0; s < 2; ++s) {
      int j = h*2 + s;
      GLDS(pp[j] + st * 64, &lds[dbase + j*4096 + wave*512]);
    }
  };

  const char* ldsb = (const char*)lds;
  auto RD = [&](int d, int op, int rr, int kk) -> bf16x8 {
    int bc = (kk*64 + lk) ^ ((rr & 7) << 4);
    return *(const bf16x8*)(ldsb + (size_t)(d*65536 + op*32768 + rr*128 + bc));
  };

  f32x4 acc[8][4];
#pragma unroll
  for (int m = 0; m < 8; ++m)
#pragma unroll
    for (int nn = 0; nn < 4; ++nn) acc[m][nn] = (f32x4){0.f,0.f,0.f,0.f};

  // prologue: tile0 fully, tile1 {A0,B0,B1}; A1(1) staged at t=0.q0
  STAGE(0,0,0); STAGE(0,1,0); STAGE(0,0,1); STAGE(0,1,1);
  STAGE(1,0,0); STAGE(1,1,0); STAGE(1,1,1);
  asm volatile("s_waitcnt vmcnt(6)" ::: "memory");    // tile0's 8 loads landed
  __builtin_amdgcn_sched_barrier(0);
  __builtin_amdgcn_s_barrier();

  bf16x8 a[4][2], b[2][2], b0h[2][2];

  for (int t = 0; t < NT; ++t) {
    const int d = t & 1;
    // ---------- q0: read A0(8)+B0(4); stage A1(t+1) ----------
#pragma unroll
    for (int m = 0; m < 4; ++m)
#pragma unroll
      for (int kk = 0; kk < 2; ++kk) a[m][kk] = RD(d, 0, wm*64 + m*16 + lr, kk);
#pragma unroll
    for (int nn = 0; nn < 2; ++nn)
#pragma unroll
      for (int kk = 0; kk < 2; ++kk) { b[nn][kk] = RD(d, 1, wn*32 + nn*16 + lr, kk); b0h[nn][kk] = b[nn][kk]; }
    STAGE((t+1) & MSK, 0, 1);
    __builtin_amdgcn_s_barrier();
    asm volatile("s_waitcnt lgkmcnt(0)" ::: "memory");
    __builtin_amdgcn_sched_barrier(0);
    __builtin_amdgcn_s_setprio(1);
#pragma unroll
    for (int m = 0; m < 4; ++m)
#pragma unroll
      for (int nn = 0; nn < 2; ++nn)
#pragma unroll
        for (int kk = 0; kk < 2; ++kk)
          acc[m][nn] = __builtin_amdgcn_mfma_f32_16x16x32_bf16(a[m][kk], b[nn][kk], acc[m][nn], 0, 0, 0);
    __builtin_amdgcn_s_setprio(0);
    __builtin_amdgcn_sched_barrier(0);
    __builtin_amdgcn_s_barrier();
    // ---------- q1: read B1(4); stage B0(t+2) ----------
#pragma unroll
    for (int nn = 0; nn < 2; ++nn)
#pragma unroll
      for (int kk = 0; kk < 2; ++kk) b[nn][kk] = RD(d, 1, 128 + wn*32 + nn*16 + lr, kk);
    STAGE((t+2) & MSK, 1, 0);
    __builtin_amdgcn_s_barrier();
    asm volatile("s_waitcnt lgkmcnt(0)" ::: "memory");
    __builtin_amdgcn_sched_barrier(0);
    __builtin_amdgcn_s_setprio(1);
#pragma unroll
    for (int m = 0; m < 4; ++m)
#pragma unroll
      for (int nn = 0; nn < 2; ++nn)
#pragma unroll
        for (int kk = 0; kk < 2; ++kk)
          acc[m][2+nn] = __builtin_amdgcn_mfma_f32_16x16x32_bf16(a[m][kk], b[nn][kk], acc[m][2+nn], 0, 0, 0);
    __builtin_amdgcn_s_setprio(0);
    __builtin_amdgcn_sched_barrier(0);
    __builtin_amdgcn_s_barrier();
    // ---------- q2: read A1(8); stage A0(t+2) ----------
#pragma unroll
    for (int m = 0; m < 4; ++m)
#pragma unroll
      for (int kk = 0; kk < 2; ++kk) a[m][kk] = RD(d, 0, 128 + wm*64 + m*16 + lr, kk);
    STAGE((t+2) & MSK, 0, 0);
    __builtin_amdgcn_s_barrier();
    asm volatile("s_waitcnt lgkmcnt(0)" ::: "memory");
    __builtin_amdgcn_sched_barrier(0);
    __builtin_amdgcn_s_setprio(1);
#pragma unroll
    for (int m = 0; m < 4; ++m)
#pragma unroll
      for (int nn = 0; nn < 2; ++nn)
#pragma unroll
        for (int kk = 0; kk < 2; ++kk)
          acc[4+m][2+nn] = __builtin_amdgcn_mfma_f32_16x16x32_bf16(a[m][kk], b[nn][kk], acc[4+m][2+nn], 0, 0, 0);
    __builtin_amdgcn_s_setprio(0);
    __builtin_amdgcn_sched_barrier(0);
    __builtin_amdgcn_s_barrier();
    // ---------- q3: no ds_reads (A1 + held B0); stage B1(t+2) ----------
    STAGE((t+2) & MSK, 1, 1);
    __builtin_amdgcn_s_barrier();
    asm volatile("s_waitcnt lgkmcnt(0)" ::: "memory");
    __builtin_amdgcn_sched_barrier(0);
    __builtin_amdgcn_s_setprio(1);
#pragma unroll
    for (int m = 0; m < 4; ++m)
#pragma unroll
      for (int nn = 0; nn < 2; ++nn)
#pragma unroll
        for (int kk = 0; kk < 2; ++kk)
          acc[4+m][nn] = __builtin_amdgcn_mfma_f32_16x16x32_bf16(a[m][kk], b0h[nn][kk], acc[4+m][nn], 0, 0, 0);
    __builtin_amdgcn_s_setprio(0);
    __builtin_amdgcn_sched_barrier(0);
    asm volatile("s_waitcnt vmcnt(6)" ::: "memory");    // K-tile boundary: tile t+1 fully landed
    __builtin_amdgcn_s_barrier();
  }

  // epilogue: C/D map col=lane&15, row=(lane>>4)*4+reg  [verified m89]
  const int rl = (lane >> 4) << 2;
  if (ACT) {
#pragma unroll
    for (int mq = 0; mq < 2; ++mq)
#pragma unroll
      for (int m = 0; m < 4; ++m) {
        int rbase = mq*128 + wm*64 + m*16 + rl;
#pragma unroll
        for (int nq = 0; nq < 2; ++nq) {
          f32x4 h1 = acc[mq*4+m][nq*2], h3 = acc[mq*4+m][nq*2+1];
          int ucol = xt*128 + nq*64 + wn*16 + lr;
#pragma unroll
          for (int j = 0; j < 4; ++j) {
            int lrow = rbase + j;
            if (lrow < rv) {
              float v1 = h1[j];
              float uu = v1 / (1.f + __expf(-v1)) * h3[j];   // silu(h1)*h3
              out[(size_t)(rowbase + brow + lrow) * IDIM + ucol] = f32_to_bf16(uu);
            }
          }
        }
      }
  } else {
#pragma unroll
    for (int mq = 0; mq < 2; ++mq)
#pragma unroll
      for (int m = 0; m < 4; ++m) {
        int rbase = mq*128 + wm*64 + m*16 + rl;
#pragma unroll
        for (int nq = 0; nq < 2; ++nq)
#pragma unroll
          for (int nn = 0; nn < 2; ++nn) {
            int col = xt*256 + nq*128 + wn*32 + nn*16 + lr;
            f32x4 v = acc[mq*4+m][nq*2+nn];
#pragma unroll
            for (int j = 0; j < 4; ++j) {
              int lrow = rbase + j;
              if (lrow < rv)
                out[(size_t)(rowbase + brow + lrow) * HDIM + col] = f32_to_bf16(v[j]);
            }
          }
      }
  }
}

// ---------------- combine: y[t] = sum_k w_k * oe[e_k][pos_k] + shared[t] ----------------
__global__ __launch_bounds__(256) void k_combine(const u16* __restrict__ oe,
                                                 const int* __restrict__ idx, const float* __restrict__ wts,
                                                 const int* __restrict__ pos, float* __restrict__ y) {
  int t = blockIdx.x;
  int h0 = threadIdx.x * 4;
  float a0 = 0, a1 = 0, a2 = 0, a3 = 0;
#pragma unroll
  for (int k = 0; k < KSEL; ++k) {
    int e = idx[t*KSEL + k];
    int p = pos[t*KSEL + k];
    if (p < CAPE) {
      float w = wts[t*KSEL + k];
      ushort4 v = *reinterpret_cast<const ushort4*>(oe + ((long)e * CAPE + p) * HDIM + h0);
      a0 += w * bf16_to_f32(v.x); a1 += w * bf16_to_f32(v.y);
      a2 += w * bf16_to_f32(v.z); a3 += w * bf16_to_f32(v.w);
    }
  }
  ushort4 s = *reinterpret_cast<const ushort4*>(oe + ((long)NEXP * CAPE + t) * HDIM + h0);
  a0 += bf16_to_f32(s.x); a1 += bf16_to_f32(s.y); a2 += bf16_to_f32(s.z); a3 += bf16_to_f32(s.w);
  float4 o2; o2.x = a0; o2.y = a1; o2.z = a2; o2.w = a3;
  reinterpret_cast<float4*>(y + (long)t * HDIM)[threadIdx.x] = o2;
}

extern "C" void kernel_launch(void* const* d_in, const int* in_sizes, int n_in,
                              void* d_out, int out_size, void* d_ws, size_t ws_size,
                              hipStream_t stream) {
  const float* x      = (const float*)d_in[0];
  const float* gate_w = (const float*)d_in[1];
  const float* w13    = (const float*)d_in[2];
  const float* w2     = (const float*)d_in[3];
  const float* sw1    = (const float*)d_in[4];
  const float* sw2    = (const float*)d_in[5];
  const float* sw3    = (const float*)d_in[6];
  float* y = (float*)d_out;

  char* base = (char*)d_ws;
  size_t off = 0;
  auto alloc = [&](size_t bytes) -> void* {
    void* p = base + off;
    off = (off + bytes + 255) & ~(size_t)255;
    return p;
  };
  u16* xb    = (u16*)alloc((size_t)T_TOK * HDIM * 2);
  u16* w13b  = (u16*)alloc((size_t)(NEXP + 1) * 2 * IDIM * HDIM * 2);
  u16* w2b   = (u16*)alloc((size_t)(NEXP + 1) * HDIM * IDIM * 2);
  u16* u_ws  = (u16*)alloc((size_t)NROW * IDIM * 2);
  u16* oe_ws = (u16*)alloc((size_t)NROW * HDIM * 2);
  int*   idx  = (int*)alloc((size_t)T_TOK * KSEL * 4);
  float* wts  = (float*)alloc((size_t)T_TOK * KSEL * 4);
  int*   pos  = (int*)alloc((size_t)T_TOK * KSEL * 4);
  int*   etok = (int*)alloc((size_t)NROW * 4);
  int*   cnts = (int*)alloc(256);
  int*   list = (int*)alloc(MAXTILE * 4);
  int*   tot  = (int*)alloc(64);
  int*   done = (int*)alloc(64);
  if (off > ws_size) return;

  // reset gate/assign rendezvous counters (graph-capture-safe)
  hipMemsetAsync(done, 0, 64, stream);

  // 1. gate (128) ∪ assign (33, gated on gates, full 1024-thread scan) ∪ w13 convert (2048)
  k_pre<<<dim3(2209), dim3(1024), 0, stream>>>(x, gate_w, w13, sw1, sw3, idx, wts, xb, w13b,
                                               etok, pos, cnts, list, tot, done);
  // 2. GEMM1 (bf16 w13b); inactive blocks convert w2+sw2 -> w2b in GEMM1's shadow
  k_gemm8<HDIM, true,  true ><<<dim3(MAXWG + CVTWG), dim3(512), 0, stream>>>(
      xb, w13b, u_ws, etok, cnts, list, tot,
      w2, sw2, w2b, (long)(NEXP + 1) * HDIM * IDIM / 8);
  // 3. GEMM2 (bf16 w2b)
  k_gemm8<IDIM, false, false><<<dim3(MAXWG), dim3(512), 0, stream>>>(
      u_ws, w2b, oe_ws, etok, cnts, list, tot,
      nullptr, nullptr, nullptr, 0L);
  // 4. combine
  k_combine<<<dim3(T_TOK), dim3(256), 0, stream>>>(oe_ws, idx, wts, pos, y);
}

// Round 11
// 274.360 us; speedup vs baseline: 1.1240x; 1.0185x over previous
//
#include <hip/hip_runtime.h>

typedef unsigned short u16;
typedef unsigned int u32;
typedef float f32x4 __attribute__((ext_vector_type(4)));
typedef __bf16 bf16x8 __attribute__((ext_vector_type(8)));

#define T_TOK 4096
#define HDIM 1024
#define IDIM 512
#define NEXP 32
#define KSEL 8
#define CAPE 2048
#define NROW (NEXP*CAPE + T_TOK)   // 69632 rows total (experts + shared)
#define MAXTILE 528                // 33 experts * 16 y-tiles max
#define MAXWG  (MAXTILE*4)         // 2112
#define CVTWG  512                 // guaranteed converter blocks appended to GEMM1

__device__ __forceinline__ u16 f32_to_bf16(float f) {
  u32 x = __float_as_uint(f);
  u32 r = (x + 0x7FFFu + ((x >> 16) & 1u)) >> 16;   // RNE; inputs finite
  return (u16)r;
}
__device__ __forceinline__ float bf16_to_f32(u16 u) {
  return __uint_as_float(((u32)u) << 16);
}

// ---------------- k_pre: gate (blocks 0..127) ∪ w13 interleave convert (blocks 128..2175) ----------------
// Gate: fp64 logits, group-limited top-k on logits (sigmoid monotonic), sigmoid only for the 8
// winners; fused x->bf16. Convert: w13 (+sw1/sw3 as expert 32) -> bf16 with 16-row w1/w3 interleave.
__global__ __launch_bounds__(256) void k_pre(const float* __restrict__ x, const float* __restrict__ gw,
                                             const float* __restrict__ w13,
                                             const float* __restrict__ sw1, const float* __restrict__ sw3,
                                             int* __restrict__ idx, float* __restrict__ wts,
                                             u16* __restrict__ xb, u16* __restrict__ w13b,
                                             int* __restrict__ done) {
  const int tid = threadIdx.x;
  if (blockIdx.x >= 128) {
    // ---- w13 convert: chunk j of 8 f32; dest row rd: c=rd>>4, even c -> w1 rows (c>>1)*16.., odd -> w3
    const long n8 = (long)(NEXP + 1) * 1024 * 128;
    const long stride = (long)(2176 - 128) * 256;
    for (long j = (long)(blockIdx.x - 128) * 256 + tid; j < n8; j += stride) {
      int e   = (int)(j >> 17);
      int rem = (int)(j & 131071);
      int rowd = rem >> 7;
      int c8   = rem & 127;
      int c = rowd >> 4, cw = rowd & 15;
      int srow = (c >> 1) * 16 + cw;
      int sel = c & 1;
      const float* s;
      if (e < NEXP) s = w13 + (size_t)e * (2 * IDIM * HDIM) + (size_t)(sel * IDIM + srow) * HDIM + c8 * 8;
      else          s = (sel ? sw3 : sw1) + (size_t)srow * HDIM + c8 * 8;
      float4 a = reinterpret_cast<const float4*>(s)[0];
      float4 b = reinterpret_cast<const float4*>(s)[1];
      ushort4 lo, hi;
      lo.x=f32_to_bf16(a.x); lo.y=f32_to_bf16(a.y); lo.z=f32_to_bf16(a.z); lo.w=f32_to_bf16(a.w);
      hi.x=f32_to_bf16(b.x); hi.y=f32_to_bf16(b.y); hi.z=f32_to_bf16(b.z); hi.w=f32_to_bf16(b.w);
      u16* d = w13b + ((size_t)e * 1024 + rowd) * HDIM + c8 * 8;
      reinterpret_cast<ushort4*>(d)[0] = lo;
      reinterpret_cast<ushort4*>(d)[1] = hi;
    }
    return;
  }
  // ---- gate path ----
  __shared__ float xs[32][129];
  __shared__ float gs_[32][129];
  __shared__ double sc[32][32];
  const int t0 = blockIdx.x * 32;
  const int tl = tid & 31, g = tid >> 5;
  if (blockIdx.x == 0 && tid == 0) done[0] = 0;   // reset rendezvous for k_assign (next launch)
  double acc0 = 0, acc1 = 0, acc2 = 0, acc3 = 0;
  for (int k0 = 0; k0 < HDIM; k0 += 128) {
#pragma unroll
    for (int q = 0; q < 4; ++q) {
      int f = tid + 256 * q;
      int row = f >> 5, c4 = (f & 31) * 4;
      float4 v = *reinterpret_cast<const float4*>(x + (long)(t0 + row) * HDIM + k0 + c4);
      xs[row][c4+0]=v.x; xs[row][c4+1]=v.y; xs[row][c4+2]=v.z; xs[row][c4+3]=v.w;
      ushort4 xv; xv.x=f32_to_bf16(v.x); xv.y=f32_to_bf16(v.y); xv.z=f32_to_bf16(v.z); xv.w=f32_to_bf16(v.w);
      *reinterpret_cast<ushort4*>(xb + (long)(t0 + row) * HDIM + k0 + c4) = xv;   // fused x convert
      float4 w = *reinterpret_cast<const float4*>(gw + (long)row * HDIM + k0 + c4);
      gs_[row][c4+0]=w.x; gs_[row][c4+1]=w.y; gs_[row][c4+2]=w.z; gs_[row][c4+3]=w.w;
    }
    __syncthreads();
#pragma unroll 4
    for (int kk = 0; kk < 128; ++kk) {
      double xv = (double)xs[tl][kk];
      acc0 += xv * (double)gs_[g     ][kk];
      acc1 += xv * (double)gs_[g +  8][kk];
      acc2 += xv * (double)gs_[g + 16][kk];
      acc3 += xv * (double)gs_[g + 24][kk];
    }
    __syncthreads();
  }
  sc[tl][g     ] = acc0;   // raw logits
  sc[tl][g +  8] = acc1;
  sc[tl][g + 16] = acc2;
  sc[tl][g + 24] = acc3;
  __syncthreads();
  if (tid < 32) {
    int t = t0 + tid;
    double gsc[8];
#pragma unroll
    for (int gg = 0; gg < 8; ++gg) {
      double mx = sc[tid][4*gg];
#pragma unroll
      for (int j = 1; j < 4; ++j) mx = fmax(mx, sc[tid][4*gg + j]);
      gsc[gg] = mx;
    }
    unsigned gmask = 0;
    for (int it = 0; it < 4; ++it) {          // top-4 groups, strict >, first index wins
      double best = -1e300; int bi = 0;
      for (int gg = 0; gg < 8; ++gg)
        if (!((gmask >> gg) & 1) && gsc[gg] > best) { best = gsc[gg]; bi = gg; }
      gmask |= 1u << bi;
    }
    unsigned emask = 0; int ei[KSEL]; double ew[KSEL]; double wsum = 0;
    for (int it = 0; it < KSEL; ++it) {       // top-8 experts on logits
      double best = -1e300; int bi = 0;
      for (int e = 0; e < NEXP; ++e)
        if (((gmask >> (e >> 2)) & 1) && !((emask >> e) & 1)) {
          double v = sc[tid][e];
          if (v > best) { best = v; bi = e; }
        }
      emask |= 1u << bi; ei[it] = bi;
      double sg = 1.0 / (1.0 + exp(-best));   // sigmoid only for selected
      ew[it] = sg; wsum += sg;
    }
    double s = 2.5 / (wsum + 1e-20);
    for (int k = 0; k < KSEL; ++k) { idx[t*KSEL + k] = ei[k]; wts[t*KSEL + k] = (float)(ew[k] * s); }
  }
}

// ---------------- capacity assignment (ballot-scan) + inline tile scheduler ----------------
__global__ __launch_bounds__(1024) void k_assign(const int* __restrict__ idx,
                                                 int* __restrict__ etok, int* __restrict__ pos,
                                                 int* __restrict__ cnts,
                                                 int* __restrict__ list, int* __restrict__ tot,
                                                 int* __restrict__ done) {
  const int e = blockIdx.x;
  const int tid = threadIdx.x;
  int base = 0;
  if (e == NEXP) {                             // shared "expert": identity token list
    for (int t = tid; t < T_TOK; t += 1024) etok[NEXP*CAPE + t] = t;
    base = T_TOK;
  } else {
    __shared__ int wbase[17];
    const int wid = tid >> 6, lane = tid & 63;
    for (int c = 0; c < T_TOK / 1024; ++c) {
      int t = c * 1024 + tid;
      int found = -1;
#pragma unroll
      for (int k = 0; k < KSEL; ++k) if (idx[t*KSEL + k] == e) found = k;
      unsigned long long mask = __ballot(found >= 0);
      int myrank = __popcll(mask & ((1ull << lane) - 1ull));
      __syncthreads();
      if (lane == 0) wbase[wid] = __popcll(mask);
      __syncthreads();
      if (tid == 0) {
        int run = 0;
#pragma unroll
        for (int w = 0; w < 16; ++w) { int v = wbase[w]; wbase[w] = run; run += v; }
        wbase[16] = run;
      }
      __syncthreads();
      if (found >= 0) {
        int slot = base + wbase[wid] + myrank;
        pos[t*KSEL + found] = slot;
        if (slot < CAPE) etok[e*CAPE + slot] = t;
      }
      base += wbase[16];
      __syncthreads();
    }
    base = min(base, CAPE);
  }
  if (tid == 0) {
    cnts[e] = base;
    __threadfence();
    if (atomicAdd(done, 1) == NEXP) {          // last finisher builds the compact work list
      __threadfence();
      int run = 0;
      for (int ee = 0; ee <= NEXP; ++ee) {
        int c = atomicAdd(&cnts[ee], 0);       // device-scope read
        int nt = (c + 255) >> 8;
        for (int i = 0; i < nt; ++i) list[run + i] = ee * 16 + i;
        run += nt;
      }
      tot[0] = run * 4;
    }
  }
}

// ---------------- grouped GEMM: 256x256 tile, BK=64, 8-phase counted-vmcnt schedule ----------------
// r3-proven inner loop: T1 bijective XCD swizzle over active prefix + T2 XOR LDS swizzle +
// T3/T4 8-phase counted vmcnt(6) + T5 setprio. Blocks beyond the active prefix run the
// fp32->bf16 converter for the NEXT GEMM's B (w2/sw2) instead of exiting (cvt_n8>0 only on GEMM1).

#define GLDS(gp, lp) __builtin_amdgcn_global_load_lds( \
    (const __attribute__((address_space(1))) void*)(gp), \
    (__attribute__((address_space(3))) void*)(lp), 16, 0, 0)

template<int KDIM, bool GATHER, bool ACT>
__global__ __launch_bounds__(512, 2) void k_gemm8(const u16* __restrict__ A, const u16* __restrict__ Ball,
                                                  u16* __restrict__ out,
                                                  const int* __restrict__ etok, const int* __restrict__ cnts,
                                                  const int* __restrict__ list, const int* __restrict__ tot,
                                                  const float* __restrict__ cvsrc, const float* __restrict__ cvsrc2,
                                                  u16* __restrict__ cvdst, long cvt_n8) {
  constexpr int NT = KDIM / 64;
  constexpr int MSK = NT - 1;
  __shared__ u16 lds[65536];            // [dbuf 2][op 2][256*64], 128 KiB

  const int n = tot[0];                 // active wg count (4 * tiles)
  const int bid0 = blockIdx.x;
  const int tid = threadIdx.x;
  if (bid0 >= n) {
    // ---- converter service: stream cvsrc (E experts) + cvsrc2 (shared) -> cvdst bf16 ----
    if (cvt_n8 > 0) {
      const long nb = (long)gridDim.x - n;
      const long stride = nb * 512;
      for (long j = (long)(bid0 - n) * 512 + tid; j < cvt_n8; j += stride) {
        int e   = (int)(j >> 16);                    // 65536 chunks per expert (H*I/8)
        int rem = (int)(j & 65535);
        const float* s = ((e < NEXP) ? cvsrc + ((size_t)e << 19) : cvsrc2) + (size_t)rem * 8;
        float4 a = reinterpret_cast<const float4*>(s)[0];
        float4 b = reinterpret_cast<const float4*>(s)[1];
        ushort4 lo, hi;
        lo.x=f32_to_bf16(a.x); lo.y=f32_to_bf16(a.y); lo.z=f32_to_bf16(a.z); lo.w=f32_to_bf16(a.w);
        hi.x=f32_to_bf16(b.x); hi.y=f32_to_bf16(b.y); hi.z=f32_to_bf16(b.z); hi.w=f32_to_bf16(b.w);
        u16* d = cvdst + ((size_t)e << 19) + (size_t)rem * 8;
        reinterpret_cast<ushort4*>(d)[0] = lo;
        reinterpret_cast<ushort4*>(d)[1] = hi;
      }
    }
    return;
  }
  // m204 bijective XCD swizzle over [0,n)
  const int q = n >> 3, r = n & 7, xc = bid0 & 7, o = bid0 >> 3;
  const int wg = (xc < r ? xc * (q + 1) : r * (q + 1) + (xc - r) * q) + o;
  const int item = list[wg >> 2];
  const int e = item >> 4, yt = item & 15, xt = wg & 3;

  const int cnt = cnts[e];
  const int brow = yt * 256;
  const int rv = min(256, cnt - brow);
  const long rowbase = (long)e * CAPE;
  const u16* Bexp = Ball + (size_t)e * (size_t)(1024 * KDIM);

  const int wave = tid >> 6, lane = tid & 63;
  const int wm = wave >> 2, wn = wave & 3;
  const int lr = lane & 15;
  const int lk = (lane >> 4) * 16;      // byte offset of this lane's K-slot

  // staging source pointers: sub-issue j covers tile rows j*64..j*64+63
  const u16* pa[4]; const u16* pb[4];
#pragma unroll
  for (int j = 0; j < 4; ++j) {
    int row = j*64 + (tid >> 3);
    int sl = (tid & 7) ^ (row & 7);                  // pre-swizzled source chunk
    long arow;
    if (GATHER) arow = (row < rv) ? (long)etok[rowbase + brow + row] : 0L;
    else        arow = rowbase + brow + row;
    pa[j] = A + arow * KDIM + sl * 8;
    pb[j] = Bexp + ((long)(xt*256 + row)) * KDIM + sl * 8;
  }

  // stage half h (0: rows 0-127, 1: rows 128-255) of operand op of K-tile st
  auto STAGE = [&](int st, int op, int h) {
    int dbase = (st & 1) * 32768 + op * 16384;
    const u16* const* pp = op ? pb : pa;
#pragma unroll
    for (int s = 0; s < 2; ++s) {
      int j = h*2 + s;
      GLDS(pp[j] + st * 64, &lds[dbase + j*4096 + wave*512]);
    }
  };

  const char* ldsb = (const char*)lds;
  auto RD = [&](int d, int op, int rr, int kk) -> bf16x8 {
    int bc = (kk*64 + lk) ^ ((rr & 7) << 4);
    return *(const bf16x8*)(ldsb + (size_t)(d*65536 + op*32768 + rr*128 + bc));
  };

  f32x4 acc[8][4];
#pragma unroll
  for (int m = 0; m < 8; ++m)
#pragma unroll
    for (int nn = 0; nn < 4; ++nn) acc[m][nn] = (f32x4){0.f,0.f,0.f,0.f};

  // prologue: tile0 fully, tile1 {A0,B0,B1}; A1(1) staged at t=0.q0
  STAGE(0,0,0); STAGE(0,1,0); STAGE(0,0,1); STAGE(0,1,1);
  STAGE(1,0,0); STAGE(1,1,0); STAGE(1,1,1);
  asm volatile("s_waitcnt vmcnt(6)" ::: "memory");    // tile0's 8 loads landed
  __builtin_amdgcn_sched_barrier(0);
  __builtin_amdgcn_s_barrier();

  bf16x8 a[4][2], b[2][2], b0h[2][2];

  for (int t = 0; t < NT; ++t) {
    const int d = t & 1;
    // ---------- q0: (mq=0,nq=0) — read A0(8)+B0(4); stage A1(t+1) ----------
#pragma unroll
    for (int m = 0; m < 4; ++m)
#pragma unroll
      for (int kk = 0; kk < 2; ++kk) a[m][kk] = RD(d, 0, wm*64 + m*16 + lr, kk);
#pragma unroll
    for (int nn = 0; nn < 2; ++nn)
#pragma unroll
      for (int kk = 0; kk < 2; ++kk) { b[nn][kk] = RD(d, 1, wn*32 + nn*16 + lr, kk); b0h[nn][kk] = b[nn][kk]; }
    STAGE((t+1) & MSK, 0, 1);
    __builtin_amdgcn_s_barrier();
    asm volatile("s_waitcnt lgkmcnt(0)" ::: "memory");
    __builtin_amdgcn_sched_barrier(0);
    __builtin_amdgcn_s_setprio(1);
#pragma unroll
    for (int m = 0; m < 4; ++m)
#pragma unroll
      for (int nn = 0; nn < 2; ++nn)
#pragma unroll
        for (int kk = 0; kk < 2; ++kk)
          acc[m][nn] = __builtin_amdgcn_mfma_f32_16x16x32_bf16(a[m][kk], b[nn][kk], acc[m][nn], 0, 0, 0);
    __builtin_amdgcn_s_setprio(0);
    __builtin_amdgcn_sched_barrier(0);
    __builtin_amdgcn_s_barrier();
    // ---------- q1: (mq=0,nq=1) — read B1(4); stage B0(t+2) ----------
#pragma unroll
    for (int nn = 0; nn < 2; ++nn)
#pragma unroll
      for (int kk = 0; kk < 2; ++kk) b[nn][kk] = RD(d, 1, 128 + wn*32 + nn*16 + lr, kk);
    STAGE((t+2) & MSK, 1, 0);
    __builtin_amdgcn_s_barrier();
    asm volatile("s_waitcnt lgkmcnt(0)" ::: "memory");
    __builtin_amdgcn_sched_barrier(0);
    __builtin_amdgcn_s_setprio(1);
#pragma unroll
    for (int m = 0; m < 4; ++m)
#pragma unroll
      for (int nn = 0; nn < 2; ++nn)
#pragma unroll
        for (int kk = 0; kk < 2; ++kk)
          acc[m][2+nn] = __builtin_amdgcn_mfma_f32_16x16x32_bf16(a[m][kk], b[nn][kk], acc[m][2+nn], 0, 0, 0);
    __builtin_amdgcn_s_setprio(0);
    __builtin_amdgcn_sched_barrier(0);
    __builtin_amdgcn_s_barrier();
    // ---------- q2: (mq=1,nq=1) — read A1(8); stage A0(t+2) ----------
#pragma unroll
    for (int m = 0; m < 4; ++m)
#pragma unroll
      for (int kk = 0; kk < 2; ++kk) a[m][kk] = RD(d, 0, 128 + wm*64 + m*16 + lr, kk);
    STAGE((t+2) & MSK, 0, 0);
    __builtin_amdgcn_s_barrier();
    asm volatile("s_waitcnt lgkmcnt(0)" ::: "memory");
    __builtin_amdgcn_sched_barrier(0);
    __builtin_amdgcn_s_setprio(1);
#pragma unroll
    for (int m = 0; m < 4; ++m)
#pragma unroll
      for (int nn = 0; nn < 2; ++nn)
#pragma unroll
        for (int kk = 0; kk < 2; ++kk)
          acc[4+m][2+nn] = __builtin_amdgcn_mfma_f32_16x16x32_bf16(a[m][kk], b[nn][kk], acc[4+m][2+nn], 0, 0, 0);
    __builtin_amdgcn_s_setprio(0);
    __builtin_amdgcn_sched_barrier(0);
    __builtin_amdgcn_s_barrier();
    // ---------- q3: (mq=1,nq=0) — no ds_reads (A1 + held B0); stage B1(t+2) ----------
    STAGE((t+2) & MSK, 1, 1);
    __builtin_amdgcn_s_barrier();
    asm volatile("s_waitcnt lgkmcnt(0)" ::: "memory");
    __builtin_amdgcn_sched_barrier(0);
    __builtin_amdgcn_s_setprio(1);
#pragma unroll
    for (int m = 0; m < 4; ++m)
#pragma unroll
      for (int nn = 0; nn < 2; ++nn)
#pragma unroll
        for (int kk = 0; kk < 2; ++kk)
          acc[4+m][nn] = __builtin_amdgcn_mfma_f32_16x16x32_bf16(a[m][kk], b0h[nn][kk], acc[4+m][nn], 0, 0, 0);
    __builtin_amdgcn_s_setprio(0);
    __builtin_amdgcn_sched_barrier(0);
    asm volatile("s_waitcnt vmcnt(6)" ::: "memory");    // K-tile boundary: tile t+1 fully landed
    __builtin_amdgcn_s_barrier();
  }

  // epilogue: C/D map col=lane&15, row=(lane>>4)*4+reg  [verified m89]
  const int rl = (lane >> 4) << 2;
  if (ACT) {
#pragma unroll
    for (int mq = 0; mq < 2; ++mq)
#pragma unroll
      for (int m = 0; m < 4; ++m) {
        int rbase = mq*128 + wm*64 + m*16 + rl;
#pragma unroll
        for (int nq = 0; nq < 2; ++nq) {
          f32x4 h1 = acc[mq*4+m][nq*2], h3 = acc[mq*4+m][nq*2+1];
          int ucol = xt*128 + nq*64 + wn*16 + lr;
#pragma unroll
          for (int j = 0; j < 4; ++j) {
            int lrow = rbase + j;
            if (lrow < rv) {
              float v1 = h1[j];
              float uu = v1 / (1.f + __expf(-v1)) * h3[j];   // silu(h1)*h3
              out[(size_t)(rowbase + brow + lrow) * IDIM + ucol] = f32_to_bf16(uu);
            }
          }
        }
      }
  } else {
#pragma unroll
    for (int mq = 0; mq < 2; ++mq)
#pragma unroll
      for (int m = 0; m < 4; ++m) {
        int rbase = mq*128 + wm*64 + m*16 + rl;
#pragma unroll
        for (int nq = 0; nq < 2; ++nq)
#pragma unroll
          for (int nn = 0; nn < 2; ++nn) {
            int col = xt*256 + nq*128 + wn*32 + nn*16 + lr;
            f32x4 v = acc[mq*4+m][nq*2+nn];
#pragma unroll
            for (int j = 0; j < 4; ++j) {
              int lrow = rbase + j;
              if (lrow < rv)
                out[(size_t)(rowbase + brow + lrow) * HDIM + col] = f32_to_bf16(v[j]);
            }
          }
      }
  }
}

// ---------------- combine: y[t] = sum_k w_k * oe[e_k][pos_k] + shared[t] ----------------
__global__ __launch_bounds__(256) void k_combine(const u16* __restrict__ oe,
                                                 const int* __restrict__ idx, const float* __restrict__ wts,
                                                 const int* __restrict__ pos, float* __restrict__ y) {
  int t = blockIdx.x;
  int h0 = threadIdx.x * 4;
  float a0 = 0, a1 = 0, a2 = 0, a3 = 0;
#pragma unroll
  for (int k = 0; k < KSEL; ++k) {
    int e = idx[t*KSEL + k];
    int p = pos[t*KSEL + k];
    if (p < CAPE) {
      float w = wts[t*KSEL + k];
      ushort4 v = *reinterpret_cast<const ushort4*>(oe + ((long)e * CAPE + p) * HDIM + h0);
      a0 += w * bf16_to_f32(v.x); a1 += w * bf16_to_f32(v.y);
      a2 += w * bf16_to_f32(v.z); a3 += w * bf16_to_f32(v.w);
    }
  }
  ushort4 s = *reinterpret_cast<const ushort4*>(oe + ((long)NEXP * CAPE + t) * HDIM + h0);
  a0 += bf16_to_f32(s.x); a1 += bf16_to_f32(s.y); a2 += bf16_to_f32(s.z); a3 += bf16_to_f32(s.w);
  float4 o2; o2.x = a0; o2.y = a1; o2.z = a2; o2.w = a3;
  reinterpret_cast<float4*>(y + (long)t * HDIM)[threadIdx.x] = o2;
}

extern "C" void kernel_launch(void* const* d_in, const int* in_sizes, int n_in,
                              void* d_out, int out_size, void* d_ws, size_t ws_size,
                              hipStream_t stream) {
  const float* x      = (const float*)d_in[0];
  const float* gate_w = (const float*)d_in[1];
  const float* w13    = (const float*)d_in[2];
  const float* w2     = (const float*)d_in[3];
  const float* sw1    = (const float*)d_in[4];
  const float* sw2    = (const float*)d_in[5];
  const float* sw3    = (const float*)d_in[6];
  float* y = (float*)d_out;

  char* base = (char*)d_ws;
  size_t off = 0;
  auto alloc = [&](size_t bytes) -> void* {
    void* p = base + off;
    off = (off + bytes + 255) & ~(size_t)255;
    return p;
  };
  u16* xb    = (u16*)alloc((size_t)T_TOK * HDIM * 2);
  u16* w13b  = (u16*)alloc((size_t)(NEXP + 1) * 2 * IDIM * HDIM * 2);
  u16* w2b   = (u16*)alloc((size_t)(NEXP + 1) * HDIM * IDIM * 2);
  u16* u_ws  = (u16*)alloc((size_t)NROW * IDIM * 2);
  u16* oe_ws = (u16*)alloc((size_t)NROW * HDIM * 2);
  int*   idx  = (int*)alloc((size_t)T_TOK * KSEL * 4);
  float* wts  = (float*)alloc((size_t)T_TOK * KSEL * 4);
  int*   pos  = (int*)alloc((size_t)T_TOK * KSEL * 4);
  int*   etok = (int*)alloc((size_t)NROW * 4);
  int*   cnts = (int*)alloc(256);
  int*   list = (int*)alloc(MAXTILE * 4);
  int*   tot  = (int*)alloc(64);
  int*   done = (int*)alloc(64);
  if (off > ws_size) return;

  // 1. gate (128 blocks) || w13+sw1/sw3 -> bf16 interleave convert (2048 blocks)
  k_pre<<<dim3(2176), dim3(256), 0, stream>>>(x, gate_w, w13, sw1, sw3, idx, wts, xb, w13b, done);
  // 2. capacity assignment + inline work-list scheduler
  k_assign<<<dim3(NEXP + 1), dim3(1024), 0, stream>>>(idx, etok, pos, cnts, list, tot, done);
  // 3. GEMM1 (bf16 w13b); inactive blocks convert w2+sw2 -> w2b in GEMM1's shadow
  k_gemm8<HDIM, true,  true ><<<dim3(MAXWG + CVTWG), dim3(512), 0, stream>>>(
      xb, w13b, u_ws, etok, cnts, list, tot,
      w2, sw2, w2b, (long)(NEXP + 1) * HDIM * IDIM / 8);
  // 4. GEMM2 (bf16 w2b)
  k_gemm8<IDIM, false, false><<<dim3(MAXWG), dim3(512), 0, stream>>>(
      u_ws, w2b, oe_ws, etok, cnts, list, tot,
      nullptr, nullptr, nullptr, 0L);
  // 5. combine
  k_combine<<<dim3(T_TOK), dim3(256), 0, stream>>>(oe_ws, idx, wts, pos, y);
}